// Round 14
// baseline (277.577 us; speedup 1.0000x reference)
//
#include <hip/hip_runtime.h>
#include <hip/hip_fp16.h>
#include <math.h>

#define N_NODES 32768
#define N_EDGES 262144
#define OUTC 54      // 16 emb + 38 msg
#define TPW  40      // tp row stride in HALVES (38 used, 16B-aligned, 80 B)
#define TGRID 64     // d0 samples per bin (65 points incl. both ends)
#define TENT 384     // floats per table entry: 16 i * 24 padded cols
#define NBINS 1345   // 21*64 in-range bins + 1 out-of-range bin

// ---------------- Kernel 1: node embeddings -----------------
__global__ __launch_bounds__(256) void node_emb_kernel(
    const float* __restrict__ x, const float* __restrict__ W1,
    const float* __restrict__ W2, float* __restrict__ out)
{
    int n = blockIdx.x * blockDim.x + threadIdx.x;
    if (n >= N_NODES) return;
    const float inv10 = 0.31622776601683794f;
    const float inv64 = 0.125f;

    float xr[10];
    #pragma unroll
    for (int i = 0; i < 10; ++i) xr[i] = x[n*10 + i];

    float t[64];
    #pragma unroll
    for (int k = 0; k < 64; ++k) {
        float acc = 0.f;
        #pragma unroll
        for (int i = 0; i < 10; ++i) acc = fmaf(xr[i], W1[i*64 + k], acc);
        t[k] = acc * inv10;
    }

    float e[16];
    #pragma unroll
    for (int j = 0; j < 16; ++j) e[j] = 0.f;
    #pragma unroll
    for (int k = 0; k < 64; ++k) {
        float tk = t[k];
        #pragma unroll
        for (int j = 0; j < 16; ++j) e[j] = fmaf(tk, W2[k*16 + j], e[j]);
    }
    #pragma unroll
    for (int j = 0; j < 16; ++j) out[n*OUTC + j] = e[j] * inv64;
}

// ---------------- bin function ------------------------------------------
__device__ __forceinline__ int edge_bin(const float* __restrict__ pos,
                                        int src, int dst)
{
    float px = pos[dst*3+0] - pos[src*3+0];
    float py = pos[dst*3+1] - pos[src*3+1];
    float pz = pos[dst*3+2] - pos[src*3+2];
    float dist = sqrtf(px*px + py*py + pz*pz + 1e-12f);
    float tt = dist * 4.2f;
    if (!(tt < 21.0f)) return NBINS - 1;     // out-of-range bin
    int m = (int)tt;
    float gf = (tt - (float)m) * (float)TGRID;
    int g0 = (int)gf; if (g0 > TGRID-1) g0 = TGRID-1;
    return m * TGRID + g0;
}

// ---------------- count: LDS histogram + cache ebin ----------------------
__global__ __launch_bounds__(256) void count_bins_kernel(
    const int* __restrict__ ei, const float* __restrict__ pos,
    int* __restrict__ cd, int* __restrict__ cb, int* __restrict__ ebin)
{
    __shared__ int hist[NBINS];
    for (int b = threadIdx.x; b < NBINS; b += 256) hist[b] = 0;
    __syncthreads();

    int e = blockIdx.x * 256 + threadIdx.x;
    int s = ei[e];
    int d = ei[N_EDGES + e];
    int bin = edge_bin(pos, s, d);
    ebin[e] = bin;
    atomicAdd(&cd[d], 1);                    // 32k addresses: cheap
    atomicAdd(&hist[bin], 1);
    __syncthreads();

    for (int b = threadIdx.x; b < NBINS; b += 256) {
        int c = hist[b];
        if (c) atomicAdd(&cb[b], c);
    }
}

// single block, 1024 threads, 32 elements each (32768 entries).
__global__ __launch_bounds__(1024) void scan_kernel(
    int* __restrict__ cursor, int* __restrict__ start)
{
    __shared__ int partial[1024];
    int tid = threadIdx.x;
    int base = tid * 32;
    int v[32];
    int s = 0;
    #pragma unroll
    for (int j = 0; j < 32; ++j) { v[j] = cursor[base + j]; s += v[j]; }
    partial[tid] = s;
    __syncthreads();
    for (int off = 1; off < 1024; off <<= 1) {
        int t = (tid >= off) ? partial[tid - off] : 0;
        __syncthreads();
        partial[tid] += t;
        __syncthreads();
    }
    int run = (tid > 0) ? partial[tid - 1] : 0;
    #pragma unroll
    for (int j = 0; j < 32; ++j) {
        start[base + j] = run;
        cursor[base + j] = run;
        run += v[j];
    }
    if (tid == 1023) start[32768] = run;
}

// ---------------- fill: two-level (LDS hist -> range reserve -> rank) -----
__global__ __launch_bounds__(256) void fill_bins_kernel(
    const int* __restrict__ ebin,
    int* __restrict__ cursor_bin,            // pre-scanned starts, consumed
    int* __restrict__ binlist, int* __restrict__ epos)
{
    __shared__ int hist[NBINS];
    __shared__ int rbase[NBINS];
    for (int b = threadIdx.x; b < NBINS; b += 256) hist[b] = 0;
    __syncthreads();

    int e = blockIdx.x * 256 + threadIdx.x;
    int bin = ebin[e];
    atomicAdd(&hist[bin], 1);
    __syncthreads();

    for (int b = threadIdx.x; b < NBINS; b += 256) {
        int c = hist[b];
        if (c) rbase[b] = atomicAdd(&cursor_bin[b], c);  // distinct addrs/wave
        hist[b] = 0;                                     // reuse as local cursor
    }
    __syncthreads();

    int lr = atomicAdd(&hist[bin], 1);       // LDS local rank
    int slot = rbase[bin] + lr;
    binlist[slot] = e;
    epos[e] = slot;
}

// ---------------- Table build: W_eff[m][g][i][c] ------------------------
__global__ __launch_bounds__(256) void table_kernel(
    const float* __restrict__ Wt1, const float* __restrict__ Wt2,
    float* __restrict__ T)
{
    int entry = blockIdx.x;            // 0 .. 21*65-1
    int m = entry / 65;
    int g = entry - m * 65;
    float d0 = (float)g * (1.0f / TGRID);
    float d1 = d0 - 1.0f;
    int j0 = m - 1, j1 = m;
    const float sq20 = 4.47213595499958f;

    float f0 = 0.f, f1 = 0.f;
    if (j0 >= 0 && j0 < 20)
        f0 = 1.14136f * expf(2.0f - 1.0f/(1.0f + d0) - 1.0f/(1.0f - d0)) * sq20;
    if (j1 >= 0 && j1 < 20)
        f1 = 1.14136f * expf(2.0f - 1.0f/(1.0f + d1) - 1.0f/(1.0f - d1)) * sq20;
    j0 = j0 < 0 ? 0 : (j0 > 19 ? 19 : j0);
    j1 = j1 < 0 ? 0 : (j1 > 19 ? 19 : j1);

    __shared__ float h[64];
    int t = threadIdx.x;
    if (t < 64) {
        float a = fmaf(f0, Wt1[j0*64 + t], f1 * Wt1[j1*64 + t])
                  * 0.22360679774997896f;
        h[t] = 1.679177f * a / (1.0f + expf(-a));
    }
    __syncthreads();

    // sc = 1/8 (w norm) * 1/4 (inv) * 1/sqrt(8) (neighbor norm)
    const float sc = 0.011048543456039806f;
    for (int e2 = t; e2 < TENT; e2 += 256) {
        int i = e2 / 24;
        int c = e2 - i * 24;
        float v = 0.f;
        if (c < 22) {
            int widx = (c < 16) ? (i*16 + c)
                     : (c < 20) ? (256 + i*4 + (c - 16))
                                : (320 + i*2 + (c - 20));
            for (int k = 0; k < 64; ++k)
                v = fmaf(h[k], Wt2[k*352 + widx], v);
            v *= sc;
        }
        T[(size_t)entry * TENT + e2] = v;
    }
}

// ---------------- Kernel 3: per-bin block, table rows in LDS -------------
// Grid = 2 blocks per in-range bin. All edges of a bin share one table
// row-pair: stage it in LDS once (3 KB), then the inner loop does ZERO
// global table loads (round-13's 192 latency-exposed loads per thread).
__global__ __launch_bounds__(256) void edge_bin_lds(
    const float* __restrict__ pos, const int* __restrict__ ei,
    const float* __restrict__ T, const float* __restrict__ outp,
    const int* __restrict__ binlist, const int* __restrict__ start_bin,
    unsigned short* __restrict__ tp, int* __restrict__ cursor,
    int* __restrict__ elist)
{
    int b    = blockIdx.x >> 1;        // bin id, 0..1343
    int part = blockIdx.x & 1;
    int s0 = start_bin[b], s1 = start_bin[b+1];
    if (s0 >= s1) return;              // empty bin (uniform exit)

    __shared__ float4 R0[TENT/4];
    __shared__ float4 R1[TENT/4];
    {
        const float4* rg = (const float4*)(T + (size_t)((b >> 6)*65 + (b & 63)) * TENT);
        for (int i = threadIdx.x; i < TENT/4; i += 256) {
            R0[i] = rg[i];
            R1[i] = rg[TENT/4 + i];    // row g0+1 is contiguous
        }
    }
    __syncthreads();

    for (int idx = s0 + part*256 + threadIdx.x; idx < s1; idx += 512) {
        int e = binlist[idx];
        int src = ei[e];
        int dst = ei[N_EDGES + e];

        int slot = atomicAdd(&cursor[dst], 1);
        elist[slot] = e;

        float px = pos[dst*3+0] - pos[src*3+0];
        float py = pos[dst*3+1] - pos[src*3+1];
        float pz = pos[dst*3+2] - pos[src*3+2];
        float dist = sqrtf(px*px + py*py + pz*pz + 1e-12f);
        float rinv = 1.0f / dist;
        float ux = px*rinv, uy = py*rinv, uz = pz*rinv;

        float tt = dist * 4.2f;
        int m  = (int)tt;
        float gf = (tt - (float)m) * (float)TGRID;
        int g0 = (int)gf; if (g0 > TGRID-1) g0 = TGRID-1;
        float fr = gf - (float)g0;

        float z[16];
        #pragma unroll
        for (int i = 0; i < 16; ++i) z[i] = outp[src*OUTC + i];

        float a0f[24], a1f[24];
        #pragma unroll
        for (int c = 0; c < 24; ++c) { a0f[c] = 0.f; a1f[c] = 0.f; }

        #pragma unroll
        for (int i = 0; i < 16; ++i) {
            float zi = z[i];
            #pragma unroll
            for (int q = 0; q < 6; ++q) {
                float4 v0 = R0[i*6 + q];     // LDS broadcast reads
                float4 v1 = R1[i*6 + q];
                a0f[q*4+0] = fmaf(zi, v0.x, a0f[q*4+0]);
                a0f[q*4+1] = fmaf(zi, v0.y, a0f[q*4+1]);
                a0f[q*4+2] = fmaf(zi, v0.z, a0f[q*4+2]);
                a0f[q*4+3] = fmaf(zi, v0.w, a0f[q*4+3]);
                a1f[q*4+0] = fmaf(zi, v1.x, a1f[q*4+0]);
                a1f[q*4+1] = fmaf(zi, v1.y, a1f[q*4+1]);
                a1f[q*4+2] = fmaf(zi, v1.z, a1f[q*4+2]);
                a1f[q*4+3] = fmaf(zi, v1.w, a1f[q*4+3]);
            }
        }

        float vals[38];
        #pragma unroll
        for (int c = 0; c < 22; ++c)
            vals[c] = fmaf(fr, a1f[c] - a0f[c], a0f[c]);   // lerp in d0

        const float s3  = 1.7320508075688772f;
        const float s15 = 3.872983346207417f;
        const float s5  = 2.23606797749979f;
        float sh1x = s3*ux, sh1y = s3*uy, sh1z = s3*uz;
        float sh2a = s15 * ux * uz;
        float sh2b = s15 * ux * uy;
        float sh2c = s5 * (uy*uy - 0.5f*(ux*ux + uz*uz));
        float sh2d = s15 * uy * uz;
        float sh2e = 0.5f * s15 * (uz*uz - ux*ux);

        // expand T first (consumes vals[20..21]), then V descending (16..19)
        #pragma unroll
        for (int u = 1; u >= 0; --u) {
            float v = vals[20 + u];
            vals[28 + u*5 + 0] = v * sh2a;
            vals[28 + u*5 + 1] = v * sh2b;
            vals[28 + u*5 + 2] = v * sh2c;
            vals[28 + u*5 + 3] = v * sh2d;
            vals[28 + u*5 + 4] = v * sh2e;
        }
        #pragma unroll
        for (int u = 3; u >= 0; --u) {
            float v = vals[16 + u];
            vals[16 + u*3 + 0] = v * sh1x;
            vals[16 + u*3 + 1] = v * sh1y;
            vals[16 + u*3 + 2] = v * sh1z;
        }

        // pack fp16, whole 80-B row per thread (coalesced, no sector RMW)
        unsigned w[20];
        #pragma unroll
        for (int j = 0; j < 19; ++j) {
            unsigned lo = __half_as_ushort(__float2half(vals[2*j]));
            unsigned hi = __half_as_ushort(__float2half(vals[2*j+1]));
            w[j] = lo | (hi << 16);
        }
        w[19] = 0;
        uint4* d4 = (uint4*)(tp + (size_t)idx * TPW);
        d4[0] = make_uint4(w[0], w[1], w[2], w[3]);
        d4[1] = make_uint4(w[4], w[5], w[6], w[7]);
        d4[2] = make_uint4(w[8], w[9], w[10], w[11]);
        d4[3] = make_uint4(w[12], w[13], w[14], w[15]);
        d4[4] = make_uint4(w[16], w[17], w[18], w[19]);
    }
}

// ---------------- tail: out-of-range bin -> zero rows + elist -------------
__global__ __launch_bounds__(256) void tail_kernel(
    const int* __restrict__ ei, const int* __restrict__ binlist,
    const int* __restrict__ start_bin,
    unsigned short* __restrict__ tp, int* __restrict__ cursor,
    int* __restrict__ elist)
{
    int s0 = start_bin[NBINS - 1];
    int idx = s0 + blockIdx.x * 256 + threadIdx.x;
    if (idx >= N_EDGES) return;
    int e = binlist[idx];
    int dst = ei[N_EDGES + e];
    elist[atomicAdd(&cursor[dst], 1)] = e;
    uint4 z4 = make_uint4(0, 0, 0, 0);
    uint4* d4 = (uint4*)(tp + (size_t)idx * TPW);
    d4[0] = z4; d4[1] = z4; d4[2] = z4; d4[3] = z4; d4[4] = z4;
}

// ---------------- Kernel 4: gather segment-sum, SORTED (deterministic) ------
__global__ __launch_bounds__(256) void gather_sorted_kernel(
    const unsigned short* __restrict__ tp, const int* __restrict__ start,
    const int* __restrict__ elist, const int* __restrict__ epos,
    float* __restrict__ out)
{
    __shared__ int sb[4][128];
    __shared__ int so[4][128];
    int wave = threadIdx.x >> 6;
    int lane = threadIdx.x & 63;
    int n = blockIdx.x * 4 + wave;          // grid == N_NODES/4, always valid
    int s0 = start[n], s1 = start[n+1];
    int K = s1 - s0;
    bool small = (K <= 128);

    if (small) {
        for (int j = lane; j < K; j += 64) sb[wave][j] = elist[s0 + j];
    }
    __syncthreads();
    if (small) {
        for (int j = lane; j < K; j += 64) {
            int v = sb[wave][j];
            int r = 0;
            for (int q = 0; q < K; ++q) r += (sb[wave][q] < v);
            so[wave][r] = v;    // edge ids distinct -> r is a permutation
        }
    }
    __syncthreads();

    if (lane < 38) {
        float acc = 0.f;
        if (small) {
            for (int j = 0; j < K; ++j)
                acc += __half2float(((const __half*)tp)
                           [(size_t)epos[so[wave][j]] * TPW + lane]);
        } else {
            for (int j = s0; j < s1; ++j)
                acc += __half2float(((const __half*)tp)
                           [(size_t)epos[elist[j]] * TPW + lane]);
        }
        out[n*OUTC + 16 + lane] = acc;
    }
}

// ---------------- fallback (atomics) if ws too small -----------------
__global__ __launch_bounds__(256) void edge_kernel_atomic(
    const float* __restrict__ pos, const int* __restrict__ ei,
    const float* __restrict__ Wt1, const float* __restrict__ Wt2,
    float* out)
{
    int e = blockIdx.x * blockDim.x + threadIdx.x;
    if (e >= N_EDGES) return;
    int src = ei[e];
    int dst = ei[N_EDGES + e];
    float px = pos[dst*3+0] - pos[src*3+0];
    float py = pos[dst*3+1] - pos[src*3+1];
    float pz = pos[dst*3+2] - pos[src*3+2];
    float dist = sqrtf(px*px + py*py + pz*pz + 1e-12f);
    float rinv = 1.0f / dist;
    float ux = px*rinv, uy = py*rinv, uz = pz*rinv;
    const float step = 5.0f / 21.0f;
    float tt = dist / step;
    int m  = (int)floorf(tt);
    int j0 = m - 1, j1 = m;
    float d0 = tt - (float)m, d1 = d0 - 1.0f;
    const float sq20 = 4.47213595499958f;
    float f0 = 0.f, f1 = 0.f;
    if (j0 >= 0 && j0 < 20)
        f0 = 1.14136f * expf(2.0f - 1.0f/(1.0f + d0) - 1.0f/(1.0f - d0)) * sq20;
    if (j1 >= 0 && j1 < 20 && d1 > -1.0f)
        f1 = 1.14136f * expf(2.0f - 1.0f/(1.0f + d1) - 1.0f/(1.0f - d1)) * sq20;
    if (f0 == 0.f && f1 == 0.f) return;
    j0 = j0 < 0 ? 0 : (j0 > 19 ? 19 : j0);
    j1 = j1 < 0 ? 0 : (j1 > 19 ? 19 : j1);
    const float* w1a = Wt1 + j0*64;
    const float* w1b = Wt1 + j1*64;
    float z[16];
    #pragma unroll
    for (int i = 0; i < 16; ++i) z[i] = out[src*OUTC + i];
    const float rsq20 = 0.22360679774997896f;
    const float snorm = 1.679177f;
    float accS[16], accV[4], accT[2];
    #pragma unroll
    for (int u = 0; u < 16; ++u) accS[u] = 0.f;
    #pragma unroll
    for (int u = 0; u < 4; ++u) accV[u] = 0.f;
    #pragma unroll
    for (int u = 0; u < 2; ++u) accT[u] = 0.f;
    for (int k = 0; k < 64; ++k) {
        float a = fmaf(f0, w1a[k], f1 * w1b[k]) * rsq20;
        float hk = snorm * a / (1.0f + expf(-a));
        const float* row = Wt2 + k*352;
        float tmp[16];
        #pragma unroll
        for (int u = 0; u < 16; ++u) tmp[u] = 0.f;
        #pragma unroll
        for (int i = 0; i < 16; ++i) {
            float zi = z[i];
            #pragma unroll
            for (int u = 0; u < 16; ++u) tmp[u] = fmaf(zi, row[i*16 + u], tmp[u]);
        }
        #pragma unroll
        for (int u = 0; u < 16; ++u) accS[u] = fmaf(hk, tmp[u], accS[u]);
        float tv[4] = {0.f,0.f,0.f,0.f};
        #pragma unroll
        for (int i = 0; i < 16; ++i) {
            float zi = z[i];
            #pragma unroll
            for (int u = 0; u < 4; ++u) tv[u] = fmaf(zi, row[256 + i*4 + u], tv[u]);
        }
        #pragma unroll
        for (int u = 0; u < 4; ++u) accV[u] = fmaf(hk, tv[u], accV[u]);
        float tw[2] = {0.f,0.f};
        #pragma unroll
        for (int i = 0; i < 16; ++i) {
            float zi = z[i];
            #pragma unroll
            for (int u = 0; u < 2; ++u) tw[u] = fmaf(zi, row[320 + i*2 + u], tw[u]);
        }
        #pragma unroll
        for (int u = 0; u < 2; ++u) accT[u] = fmaf(hk, tw[u], accT[u]);
    }
    const float sc = 0.125f * 0.25f * 0.35355339059327373f;
    const float s3  = 1.7320508075688772f;
    const float s15 = 3.872983346207417f;
    const float s5  = 2.23606797749979f;
    float sh1x = s3*ux, sh1y = s3*uy, sh1z = s3*uz;
    float sh2[5];
    sh2[0] = s15 * ux * uz;
    sh2[1] = s15 * ux * uy;
    sh2[2] = s5 * (uy*uy - 0.5f*(ux*ux + uz*uz));
    sh2[3] = s15 * uy * uz;
    sh2[4] = 0.5f * s15 * (uz*uz - ux*ux);
    float* orow = out + dst*OUTC + 16;
    #pragma unroll
    for (int u = 0; u < 16; ++u) atomicAdd(&orow[u], accS[u] * sc);
    #pragma unroll
    for (int u = 0; u < 4; ++u) {
        float v = accV[u] * sc;
        atomicAdd(&orow[16 + u*3 + 0], v * sh1x);
        atomicAdd(&orow[16 + u*3 + 1], v * sh1y);
        atomicAdd(&orow[16 + u*3 + 2], v * sh1z);
    }
    #pragma unroll
    for (int u = 0; u < 2; ++u) {
        float v = accT[u] * sc;
        #pragma unroll
        for (int mm = 0; mm < 5; ++mm)
            atomicAdd(&orow[28 + u*5 + mm], v * sh2[mm]);
    }
}

extern "C" void kernel_launch(void* const* d_in, const int* in_sizes, int n_in,
                              void* d_out, int out_size, void* d_ws, size_t ws_size,
                              hipStream_t stream) {
    const float* x   = (const float*)d_in[0];
    const float* pos = (const float*)d_in[1];
    const int*   ei  = (const int*)d_in[2];
    const float* We1 = (const float*)d_in[3];
    const float* We2 = (const float*)d_in[4];
    const float* Wt1 = (const float*)d_in[5];
    const float* Wt2 = (const float*)d_in[6];
    float* out = (float*)d_out;

    char* base = (char*)d_ws;
    size_t off = 0;
    unsigned short* tp = (unsigned short*)(base + off);
    off += (size_t)N_EDGES * TPW * 2;                    // fp16 rows, 16B-aligned
    float* T  = (float*)(base + off);       off += (size_t)21 * 65 * TENT * 4;  // 2.1 MB
    int* cursor_dst = (int*)(base + off);   off += (size_t)32768 * 4;
    int* cursor_bin = (int*)(base + off);   off += (size_t)32768 * 4;   // adjacent: one memset
    int* start_dst  = (int*)(base + off);   off += (size_t)32769 * 4;
    int* start_bin  = (int*)(base + off);   off += (size_t)32769 * 4;
    int* elist   = (int*)(base + off);      off += (size_t)N_EDGES * 4;
    int* binlist = (int*)(base + off);      off += (size_t)N_EDGES * 4;
    int* epos    = (int*)(base + off);      off += (size_t)N_EDGES * 4;
    int* ebin    = (int*)(base + off);      off += (size_t)N_EDGES * 4;
    size_t need = off;

    node_emb_kernel<<<N_NODES/256, 256, 0, stream>>>(x, We1, We2, out);

    if (ws_size >= need) {
        table_kernel<<<21*65, 256, 0, stream>>>(Wt1, Wt2, T);
        hipMemsetAsync(cursor_dst, 0, (size_t)2 * 32768 * 4, stream);
        count_bins_kernel<<<N_EDGES/256, 256, 0, stream>>>(ei, pos, cursor_dst,
                                                           cursor_bin, ebin);
        scan_kernel<<<1, 1024, 0, stream>>>(cursor_dst, start_dst);
        scan_kernel<<<1, 1024, 0, stream>>>(cursor_bin, start_bin);
        fill_bins_kernel<<<N_EDGES/256, 256, 0, stream>>>(ebin, cursor_bin,
                                                          binlist, epos);
        edge_bin_lds<<<2*(NBINS-1), 256, 0, stream>>>(pos, ei, T, out,
                                                      binlist, start_bin,
                                                      tp, cursor_dst, elist);
        tail_kernel<<<N_EDGES/256, 256, 0, stream>>>(ei, binlist, start_bin,
                                                     tp, cursor_dst, elist);
        gather_sorted_kernel<<<N_NODES/4, 256, 0, stream>>>(tp, start_dst,
                                                            elist, epos, out);
    } else {
        hipMemsetAsync(out, 0, (size_t)out_size * sizeof(float), stream);
        node_emb_kernel<<<N_NODES/256, 256, 0, stream>>>(x, We1, We2, out);
        edge_kernel_atomic<<<N_EDGES/256, 256, 0, stream>>>(pos, ei, Wt1, Wt2, out);
    }
}

// Round 16
// 221.226 us; speedup vs baseline: 1.2547x; 1.2547x over previous
//
#include <hip/hip_runtime.h>
#include <hip/hip_fp16.h>
#include <math.h>

#define N_NODES 32768
#define N_EDGES 262144
#define OUTC 54      // 16 emb + 38 msg
#define TPW  40      // tp row stride in HALVES (38 used, 80 B, 16B-aligned)
#define TGRID 64     // d0 samples per bin (65 points incl. both ends)
#define TENT 384     // floats per table entry: 16 i * 24 padded cols
#define NBINS 1345   // 21*64 in-range bins + 1 out-of-range bin

__device__ __forceinline__ unsigned pkh(float a, float b) {
    auto r = __builtin_amdgcn_cvt_pkrtz(a, b);   // v_cvt_pkrtz_f16_f32
    union { decltype(r) v; unsigned u; } cv;
    cv.v = r;
    return cv.u;
}

// ---------------- Kernel 1: node embeddings (+ aligned z copy) -----------
__global__ __launch_bounds__(256) void node_emb_kernel(
    const float* __restrict__ x, const float* __restrict__ W1,
    const float* __restrict__ W2, float* __restrict__ out,
    float* __restrict__ znode)
{
    int n = blockIdx.x * blockDim.x + threadIdx.x;
    if (n >= N_NODES) return;
    const float inv10 = 0.31622776601683794f;
    const float inv64 = 0.125f;

    float xr[10];
    #pragma unroll
    for (int i = 0; i < 10; ++i) xr[i] = x[n*10 + i];

    float t[64];
    #pragma unroll
    for (int k = 0; k < 64; ++k) {
        float acc = 0.f;
        #pragma unroll
        for (int i = 0; i < 10; ++i) acc = fmaf(xr[i], W1[i*64 + k], acc);
        t[k] = acc * inv10;
    }

    float e[16];
    #pragma unroll
    for (int j = 0; j < 16; ++j) e[j] = 0.f;
    #pragma unroll
    for (int k = 0; k < 64; ++k) {
        float tk = t[k];
        #pragma unroll
        for (int j = 0; j < 16; ++j) e[j] = fmaf(tk, W2[k*16 + j], e[j]);
    }
    float4* zb = (float4*)(znode + (size_t)n * 16);
    #pragma unroll
    for (int q = 0; q < 4; ++q) {
        float4 v = make_float4(e[q*4+0]*inv64, e[q*4+1]*inv64,
                               e[q*4+2]*inv64, e[q*4+3]*inv64);
        zb[q] = v;
        out[n*OUTC + q*4 + 0] = v.x;
        out[n*OUTC + q*4 + 1] = v.y;
        out[n*OUTC + q*4 + 2] = v.z;
        out[n*OUTC + q*4 + 3] = v.w;
    }
}

// ---------------- bin function ------------------------------------------
__device__ __forceinline__ int edge_bin(const float* __restrict__ pos,
                                        int src, int dst)
{
    float px = pos[dst*3+0] - pos[src*3+0];
    float py = pos[dst*3+1] - pos[src*3+1];
    float pz = pos[dst*3+2] - pos[src*3+2];
    float dist = sqrtf(px*px + py*py + pz*pz + 1e-12f);
    float tt = dist * 4.2f;
    if (!(tt < 21.0f)) return NBINS - 1;     // out-of-range bin
    int m = (int)tt;
    float gf = (tt - (float)m) * (float)TGRID;
    int g0 = (int)gf; if (g0 > TGRID-1) g0 = TGRID-1;
    return m * TGRID + g0;
}

// ---------------- count: LDS histogram + cache ebin ----------------------
__global__ __launch_bounds__(256) void count_bins_kernel(
    const int* __restrict__ ei, const float* __restrict__ pos,
    int* __restrict__ cd, int* __restrict__ cb, int* __restrict__ ebin)
{
    __shared__ int hist[NBINS];
    for (int b = threadIdx.x; b < NBINS; b += 256) hist[b] = 0;
    __syncthreads();

    int e = blockIdx.x * 256 + threadIdx.x;
    int s = ei[e];
    int d = ei[N_EDGES + e];
    int bin = edge_bin(pos, s, d);
    ebin[e] = bin;
    atomicAdd(&cd[d], 1);                    // 32k addresses: cheap
    atomicAdd(&hist[bin], 1);
    __syncthreads();

    for (int b = threadIdx.x; b < NBINS; b += 256) {
        int c = hist[b];
        if (c) atomicAdd(&cb[b], c);
    }
}

// dual scan: block 0 scans (c0,s0), block 1 scans (c1,s1). 32768 each.
__global__ __launch_bounds__(1024) void scan2_kernel(
    int* __restrict__ c0, int* __restrict__ s0arr,
    int* __restrict__ c1, int* __restrict__ s1arr)
{
    int* cursor = (blockIdx.x == 0) ? c0 : c1;
    int* start  = (blockIdx.x == 0) ? s0arr : s1arr;
    __shared__ int partial[1024];
    int tid = threadIdx.x;
    int base = tid * 32;
    int v[32];
    int s = 0;
    #pragma unroll
    for (int j = 0; j < 32; ++j) { v[j] = cursor[base + j]; s += v[j]; }
    partial[tid] = s;
    __syncthreads();
    for (int off = 1; off < 1024; off <<= 1) {
        int t = (tid >= off) ? partial[tid - off] : 0;
        __syncthreads();
        partial[tid] += t;
        __syncthreads();
    }
    int run = (tid > 0) ? partial[tid - 1] : 0;
    #pragma unroll
    for (int j = 0; j < 32; ++j) {
        start[base + j] = run;
        cursor[base + j] = run;
        run += v[j];
    }
    if (tid == 1023) start[32768] = run;
}

// ---------------- fill: two-level (LDS hist -> range reserve -> rank) -----
__global__ __launch_bounds__(256) void fill_bins_kernel(
    const int* __restrict__ ebin,
    int* __restrict__ cursor_bin,            // pre-scanned starts, consumed
    int* __restrict__ binlist, int* __restrict__ epos)
{
    __shared__ int hist[NBINS];
    __shared__ int rbase[NBINS];
    for (int b = threadIdx.x; b < NBINS; b += 256) hist[b] = 0;
    __syncthreads();

    int e = blockIdx.x * 256 + threadIdx.x;
    int bin = ebin[e];
    atomicAdd(&hist[bin], 1);
    __syncthreads();

    for (int b = threadIdx.x; b < NBINS; b += 256) {
        int c = hist[b];
        if (c) rbase[b] = atomicAdd(&cursor_bin[b], c);  // distinct addrs/wave
        hist[b] = 0;                                     // reuse as local cursor
    }
    __syncthreads();

    int lr = atomicAdd(&hist[bin], 1);       // LDS local rank
    int slot = rbase[bin] + lr;
    binlist[slot] = e;
    epos[e] = slot;
}

// ---------------- Table build: W_eff[m][g][i][c] ------------------------
__global__ __launch_bounds__(256) void table_kernel(
    const float* __restrict__ Wt1, const float* __restrict__ Wt2,
    float* __restrict__ T)
{
    int entry = blockIdx.x;            // 0 .. 21*65-1
    int m = entry / 65;
    int g = entry - m * 65;
    float d0 = (float)g * (1.0f / TGRID);
    float d1 = d0 - 1.0f;
    int j0 = m - 1, j1 = m;
    const float sq20 = 4.47213595499958f;

    float f0 = 0.f, f1 = 0.f;
    if (j0 >= 0 && j0 < 20)
        f0 = 1.14136f * expf(2.0f - 1.0f/(1.0f + d0) - 1.0f/(1.0f - d0)) * sq20;
    if (j1 >= 0 && j1 < 20)
        f1 = 1.14136f * expf(2.0f - 1.0f/(1.0f + d1) - 1.0f/(1.0f - d1)) * sq20;
    j0 = j0 < 0 ? 0 : (j0 > 19 ? 19 : j0);
    j1 = j1 < 0 ? 0 : (j1 > 19 ? 19 : j1);

    __shared__ float h[64];
    int t = threadIdx.x;
    if (t < 64) {
        float a = fmaf(f0, Wt1[j0*64 + t], f1 * Wt1[j1*64 + t])
                  * 0.22360679774997896f;
        h[t] = 1.679177f * a / (1.0f + expf(-a));
    }
    __syncthreads();

    // sc = 1/8 (w norm) * 1/4 (inv) * 1/sqrt(8) (neighbor norm)
    const float sc = 0.011048543456039806f;
    for (int e2 = t; e2 < TENT; e2 += 256) {
        int i = e2 / 24;
        int c = e2 - i * 24;
        float v = 0.f;
        if (c < 22) {
            int widx = (c < 16) ? (i*16 + c)
                     : (c < 20) ? (256 + i*4 + (c - 16))
                                : (320 + i*2 + (c - 20));
            for (int k = 0; k < 64; ++k)
                v = fmaf(h[k], Wt2[k*352 + widx], v);
            v *= sc;
        }
        T[(size_t)entry * TENT + e2] = v;
    }
}

// ---------------- Kernel 3: binned per-edge lerp + contract --------------
// Thread-per-edge (VGPR ~60, occupancy-friendly); wave shares 1-2 table
// rows via binning -> broadcast loads; fp16 tp row per thread (80 B).
__global__ __launch_bounds__(256) void edge_table_binned(
    const float* __restrict__ pos, const int* __restrict__ ei,
    const float* __restrict__ T, const float* __restrict__ znode,
    const int* __restrict__ binlist,
    unsigned short* __restrict__ tp, int* __restrict__ cursor,
    int* __restrict__ elist)
{
    int idx = blockIdx.x * 256 + threadIdx.x;
    int e = binlist[idx];
    int src = ei[e];
    int dst = ei[N_EDGES + e];

    int slot = atomicAdd(&cursor[dst], 1);
    elist[slot] = e;

    uint4* d4 = (uint4*)(tp + (size_t)idx * TPW);   // binned layout

    float px = pos[dst*3+0] - pos[src*3+0];
    float py = pos[dst*3+1] - pos[src*3+1];
    float pz = pos[dst*3+2] - pos[src*3+2];
    float dist = sqrtf(px*px + py*py + pz*pz + 1e-12f);
    float rinv = 1.0f / dist;
    float ux = px*rinv, uy = py*rinv, uz = pz*rinv;

    float tt = dist * 4.2f;          // dist / (5/21)
    if (!(tt < 21.0f)) {             // out of radial range -> zero message
        uint4 z4 = make_uint4(0, 0, 0, 0);
        d4[0] = z4; d4[1] = z4; d4[2] = z4; d4[3] = z4; d4[4] = z4;
        return;
    }
    int m  = (int)tt;                // 0..20
    float d0 = tt - (float)m;
    float gf = d0 * (float)TGRID;
    int g0 = (int)gf; if (g0 > TGRID-1) g0 = TGRID-1;
    float fr = gf - (float)g0;

    const float4* r0 = (const float4*)(T + (size_t)(m*65 + g0) * TENT);
    const float4* r1 = r0 + (TENT/4);    // next d0 grid point (contiguous)

    // aligned vector z loads
    const float4* zp = (const float4*)(znode + (size_t)src * 16);
    float4 zq0 = zp[0], zq1 = zp[1], zq2 = zp[2], zq3 = zp[3];
    float z[16] = {zq0.x, zq0.y, zq0.z, zq0.w,
                   zq1.x, zq1.y, zq1.z, zq1.w,
                   zq2.x, zq2.y, zq2.z, zq2.w,
                   zq3.x, zq3.y, zq3.z, zq3.w};

    float a0f[24], a1f[24];
    #pragma unroll
    for (int c = 0; c < 24; ++c) { a0f[c] = 0.f; a1f[c] = 0.f; }

    #pragma unroll
    for (int i = 0; i < 16; ++i) {
        float zi = z[i];
        #pragma unroll
        for (int q = 0; q < 6; ++q) {
            float4 v0 = r0[i*6 + q];
            float4 v1 = r1[i*6 + q];
            a0f[q*4+0] = fmaf(zi, v0.x, a0f[q*4+0]);
            a0f[q*4+1] = fmaf(zi, v0.y, a0f[q*4+1]);
            a0f[q*4+2] = fmaf(zi, v0.z, a0f[q*4+2]);
            a0f[q*4+3] = fmaf(zi, v0.w, a0f[q*4+3]);
            a1f[q*4+0] = fmaf(zi, v1.x, a1f[q*4+0]);
            a1f[q*4+1] = fmaf(zi, v1.y, a1f[q*4+1]);
            a1f[q*4+2] = fmaf(zi, v1.z, a1f[q*4+2]);
            a1f[q*4+3] = fmaf(zi, v1.w, a1f[q*4+3]);
        }
    }

    float vals[38];
    #pragma unroll
    for (int c = 0; c < 22; ++c)
        vals[c] = fmaf(fr, a1f[c] - a0f[c], a0f[c]);   // lerp in d0

    const float s3  = 1.7320508075688772f;
    const float s15 = 3.872983346207417f;
    const float s5  = 2.23606797749979f;
    float sh1x = s3*ux, sh1y = s3*uy, sh1z = s3*uz;
    float sh2a = s15 * ux * uz;
    float sh2b = s15 * ux * uy;
    float sh2c = s5 * (uy*uy - 0.5f*(ux*ux + uz*uz));
    float sh2d = s15 * uy * uz;
    float sh2e = 0.5f * s15 * (uz*uz - ux*ux);

    // expand T first (consumes vals[20..21]), then V descending (16..19)
    #pragma unroll
    for (int u = 1; u >= 0; --u) {
        float v = vals[20 + u];
        vals[28 + u*5 + 0] = v * sh2a;
        vals[28 + u*5 + 1] = v * sh2b;
        vals[28 + u*5 + 2] = v * sh2c;
        vals[28 + u*5 + 3] = v * sh2d;
        vals[28 + u*5 + 4] = v * sh2e;
    }
    #pragma unroll
    for (int u = 3; u >= 0; --u) {
        float v = vals[16 + u];
        vals[16 + u*3 + 0] = v * sh1x;
        vals[16 + u*3 + 1] = v * sh1y;
        vals[16 + u*3 + 2] = v * sh1z;
    }

    // fp16 pack, whole 80-B row per thread (coalesced, no sector RMW)
    d4[0] = make_uint4(pkh(vals[0], vals[1]),  pkh(vals[2], vals[3]),
                       pkh(vals[4], vals[5]),  pkh(vals[6], vals[7]));
    d4[1] = make_uint4(pkh(vals[8], vals[9]),  pkh(vals[10], vals[11]),
                       pkh(vals[12], vals[13]),pkh(vals[14], vals[15]));
    d4[2] = make_uint4(pkh(vals[16], vals[17]),pkh(vals[18], vals[19]),
                       pkh(vals[20], vals[21]),pkh(vals[22], vals[23]));
    d4[3] = make_uint4(pkh(vals[24], vals[25]),pkh(vals[26], vals[27]),
                       pkh(vals[28], vals[29]),pkh(vals[30], vals[31]));
    d4[4] = make_uint4(pkh(vals[32], vals[33]),pkh(vals[34], vals[35]),
                       pkh(vals[36], vals[37]),0);
}

// ---------------- Kernel 4: gather segment-sum, SORTED (deterministic) ------
__global__ __launch_bounds__(256) void gather_sorted_kernel(
    const unsigned short* __restrict__ tp, const int* __restrict__ start,
    const int* __restrict__ elist, const int* __restrict__ epos,
    float* __restrict__ out)
{
    __shared__ int sb[4][128];
    __shared__ int so[4][128];
    int wave = threadIdx.x >> 6;
    int lane = threadIdx.x & 63;
    int n = blockIdx.x * 4 + wave;          // grid == N_NODES/4, always valid
    int s0 = start[n], s1 = start[n+1];
    int K = s1 - s0;
    bool small = (K <= 128);

    if (small) {
        for (int j = lane; j < K; j += 64) sb[wave][j] = elist[s0 + j];
    }
    __syncthreads();
    if (small) {
        for (int j = lane; j < K; j += 64) {
            int v = sb[wave][j];
            int r = 0;
            for (int q = 0; q < K; ++q) r += (sb[wave][q] < v);
            so[wave][r] = v;    // edge ids distinct -> r is a permutation
        }
    }
    __syncthreads();

    if (lane < 38) {
        float acc = 0.f;
        if (small) {
            for (int j = 0; j < K; ++j)
                acc += __half2float(((const __half*)tp)
                           [(size_t)epos[so[wave][j]] * TPW + lane]);
        } else {
            for (int j = s0; j < s1; ++j)
                acc += __half2float(((const __half*)tp)
                           [(size_t)epos[elist[j]] * TPW + lane]);
        }
        out[n*OUTC + 16 + lane] = acc;
    }
}

// ---------------- fallback (atomics) if ws too small -----------------
__global__ __launch_bounds__(256) void edge_kernel_atomic(
    const float* __restrict__ pos, const int* __restrict__ ei,
    const float* __restrict__ Wt1, const float* __restrict__ Wt2,
    float* out)
{
    int e = blockIdx.x * blockDim.x + threadIdx.x;
    if (e >= N_EDGES) return;
    int src = ei[e];
    int dst = ei[N_EDGES + e];
    float px = pos[dst*3+0] - pos[src*3+0];
    float py = pos[dst*3+1] - pos[src*3+1];
    float pz = pos[dst*3+2] - pos[src*3+2];
    float dist = sqrtf(px*px + py*py + pz*pz + 1e-12f);
    float rinv = 1.0f / dist;
    float ux = px*rinv, uy = py*rinv, uz = pz*rinv;
    const float step = 5.0f / 21.0f;
    float tt = dist / step;
    int m  = (int)floorf(tt);
    int j0 = m - 1, j1 = m;
    float d0 = tt - (float)m, d1 = d0 - 1.0f;
    const float sq20 = 4.47213595499958f;
    float f0 = 0.f, f1 = 0.f;
    if (j0 >= 0 && j0 < 20)
        f0 = 1.14136f * expf(2.0f - 1.0f/(1.0f + d0) - 1.0f/(1.0f - d0)) * sq20;
    if (j1 >= 0 && j1 < 20 && d1 > -1.0f)
        f1 = 1.14136f * expf(2.0f - 1.0f/(1.0f + d1) - 1.0f/(1.0f - d1)) * sq20;
    if (f0 == 0.f && f1 == 0.f) return;
    j0 = j0 < 0 ? 0 : (j0 > 19 ? 19 : j0);
    j1 = j1 < 0 ? 0 : (j1 > 19 ? 19 : j1);
    const float* w1a = Wt1 + j0*64;
    const float* w1b = Wt1 + j1*64;
    float z[16];
    #pragma unroll
    for (int i = 0; i < 16; ++i) z[i] = out[src*OUTC + i];
    const float rsq20 = 0.22360679774997896f;
    const float snorm = 1.679177f;
    float accS[16], accV[4], accT[2];
    #pragma unroll
    for (int u = 0; u < 16; ++u) accS[u] = 0.f;
    #pragma unroll
    for (int u = 0; u < 4; ++u) accV[u] = 0.f;
    #pragma unroll
    for (int u = 0; u < 2; ++u) accT[u] = 0.f;
    for (int k = 0; k < 64; ++k) {
        float a = fmaf(f0, w1a[k], f1 * w1b[k]) * rsq20;
        float hk = snorm * a / (1.0f + expf(-a));
        const float* row = Wt2 + k*352;
        float tmp[16];
        #pragma unroll
        for (int u = 0; u < 16; ++u) tmp[u] = 0.f;
        #pragma unroll
        for (int i = 0; i < 16; ++i) {
            float zi = z[i];
            #pragma unroll
            for (int u = 0; u < 16; ++u) tmp[u] = fmaf(zi, row[i*16 + u], tmp[u]);
        }
        #pragma unroll
        for (int u = 0; u < 16; ++u) accS[u] = fmaf(hk, tmp[u], accS[u]);
        float tv[4] = {0.f,0.f,0.f,0.f};
        #pragma unroll
        for (int i = 0; i < 16; ++i) {
            float zi = z[i];
            #pragma unroll
            for (int u = 0; u < 4; ++u) tv[u] = fmaf(zi, row[256 + i*4 + u], tv[u]);
        }
        #pragma unroll
        for (int u = 0; u < 4; ++u) accV[u] = fmaf(hk, tv[u], accV[u]);
        float tw[2] = {0.f,0.f};
        #pragma unroll
        for (int i = 0; i < 16; ++i) {
            float zi = z[i];
            #pragma unroll
            for (int u = 0; u < 2; ++u) tw[u] = fmaf(zi, row[320 + i*2 + u], tw[u]);
        }
        #pragma unroll
        for (int u = 0; u < 2; ++u) accT[u] = fmaf(hk, tw[u], accT[u]);
    }
    const float sc = 0.125f * 0.25f * 0.35355339059327373f;
    const float s3  = 1.7320508075688772f;
    const float s15 = 3.872983346207417f;
    const float s5  = 2.23606797749979f;
    float sh1x = s3*ux, sh1y = s3*uy, sh1z = s3*uz;
    float sh2[5];
    sh2[0] = s15 * ux * uz;
    sh2[1] = s15 * ux * uy;
    sh2[2] = s5 * (uy*uy - 0.5f*(ux*ux + uz*uz));
    sh2[3] = s15 * uy * uz;
    sh2[4] = 0.5f * s15 * (uz*uz - ux*ux);
    float* orow = out + dst*OUTC + 16;
    #pragma unroll
    for (int u = 0; u < 16; ++u) atomicAdd(&orow[u], accS[u] * sc);
    #pragma unroll
    for (int u = 0; u < 4; ++u) {
        float v = accV[u] * sc;
        atomicAdd(&orow[16 + u*3 + 0], v * sh1x);
        atomicAdd(&orow[16 + u*3 + 1], v * sh1y);
        atomicAdd(&orow[16 + u*3 + 2], v * sh1z);
    }
    #pragma unroll
    for (int u = 0; u < 2; ++u) {
        float v = accT[u] * sc;
        #pragma unroll
        for (int mm = 0; mm < 5; ++mm)
            atomicAdd(&orow[28 + u*5 + mm], v * sh2[mm]);
    }
}

extern "C" void kernel_launch(void* const* d_in, const int* in_sizes, int n_in,
                              void* d_out, int out_size, void* d_ws, size_t ws_size,
                              hipStream_t stream) {
    const float* x   = (const float*)d_in[0];
    const float* pos = (const float*)d_in[1];
    const int*   ei  = (const int*)d_in[2];
    const float* We1 = (const float*)d_in[3];
    const float* We2 = (const float*)d_in[4];
    const float* Wt1 = (const float*)d_in[5];
    const float* Wt2 = (const float*)d_in[6];
    float* out = (float*)d_out;

    char* base = (char*)d_ws;
    size_t off = 0;
    unsigned short* tp = (unsigned short*)(base + off);
    off += (size_t)N_EDGES * TPW * 2;                    // fp16 rows, 21 MB
    float* T  = (float*)(base + off);       off += (size_t)21 * 65 * TENT * 4;  // 2.1 MB
    float* znode = (float*)(base + off);    off += (size_t)N_NODES * 16 * 4;    // 2 MB
    int* cursor_dst = (int*)(base + off);   off += (size_t)32768 * 4;
    int* cursor_bin = (int*)(base + off);   off += (size_t)32768 * 4;   // adjacent: one memset
    int* start_dst  = (int*)(base + off);   off += (size_t)32769 * 4;
    int* start_bin  = (int*)(base + off);   off += (size_t)32769 * 4;
    int* elist   = (int*)(base + off);      off += (size_t)N_EDGES * 4;
    int* binlist = (int*)(base + off);      off += (size_t)N_EDGES * 4;
    int* epos    = (int*)(base + off);      off += (size_t)N_EDGES * 4;
    int* ebin    = (int*)(base + off);      off += (size_t)N_EDGES * 4;
    size_t need = off;

    if (ws_size >= need) {
        node_emb_kernel<<<N_NODES/256, 256, 0, stream>>>(x, We1, We2, out, znode);
        table_kernel<<<21*65, 256, 0, stream>>>(Wt1, Wt2, T);
        hipMemsetAsync(cursor_dst, 0, (size_t)2 * 32768 * 4, stream);
        count_bins_kernel<<<N_EDGES/256, 256, 0, stream>>>(ei, pos, cursor_dst,
                                                           cursor_bin, ebin);
        scan2_kernel<<<2, 1024, 0, stream>>>(cursor_dst, start_dst,
                                             cursor_bin, start_bin);
        fill_bins_kernel<<<N_EDGES/256, 256, 0, stream>>>(ebin, cursor_bin,
                                                          binlist, epos);
        edge_table_binned<<<N_EDGES/256, 256, 0, stream>>>(pos, ei, T, znode,
                                                           binlist, tp,
                                                           cursor_dst, elist);
        gather_sorted_kernel<<<N_NODES/4, 256, 0, stream>>>(tp, start_dst,
                                                            elist, epos, out);
    } else {
        hipMemsetAsync(out, 0, (size_t)out_size * sizeof(float), stream);
        node_emb_kernel<<<N_NODES/256, 256, 0, stream>>>(x, We1, We2, out,
                                                         (float*)d_ws);
        edge_kernel_atomic<<<N_EDGES/256, 256, 0, stream>>>(pos, ei, Wt1, Wt2, out);
    }
}

// Round 17
// 204.336 us; speedup vs baseline: 1.3584x; 1.0827x over previous
//
#include <hip/hip_runtime.h>
#include <hip/hip_fp16.h>
#include <math.h>

#define N_NODES 32768
#define N_EDGES 262144
#define OUTC 54      // 16 emb + 38 msg
#define TPW  40      // tp row stride in HALVES (38 used, 80 B, 16B-aligned)
#define TGRID 64     // d0 samples per bin (65 points incl. both ends)
#define TENT 384     // floats per table entry: 16 i * 24 padded cols
#define NBINS 1345   // 21*64 in-range bins + 1 out-of-range bin

__device__ __forceinline__ unsigned pkh(float a, float b) {
    auto r = __builtin_amdgcn_cvt_pkrtz(a, b);   // v_cvt_pkrtz_f16_f32
    union { decltype(r) v; unsigned u; } cv;
    cv.v = r;
    return cv.u;
}

// ---------------- Kernel 1: node embeddings (+ aligned z copy) -----------
__global__ __launch_bounds__(256) void node_emb_kernel(
    const float* __restrict__ x, const float* __restrict__ W1,
    const float* __restrict__ W2, float* __restrict__ out,
    float* __restrict__ znode)
{
    int n = blockIdx.x * blockDim.x + threadIdx.x;
    if (n >= N_NODES) return;
    const float inv10 = 0.31622776601683794f;
    const float inv64 = 0.125f;

    float xr[10];
    #pragma unroll
    for (int i = 0; i < 10; ++i) xr[i] = x[n*10 + i];

    float t[64];
    #pragma unroll
    for (int k = 0; k < 64; ++k) {
        float acc = 0.f;
        #pragma unroll
        for (int i = 0; i < 10; ++i) acc = fmaf(xr[i], W1[i*64 + k], acc);
        t[k] = acc * inv10;
    }

    float e[16];
    #pragma unroll
    for (int j = 0; j < 16; ++j) e[j] = 0.f;
    #pragma unroll
    for (int k = 0; k < 64; ++k) {
        float tk = t[k];
        #pragma unroll
        for (int j = 0; j < 16; ++j) e[j] = fmaf(tk, W2[k*16 + j], e[j]);
    }
    float4* zb = (float4*)(znode + (size_t)n * 16);
    #pragma unroll
    for (int q = 0; q < 4; ++q) {
        float4 v = make_float4(e[q*4+0]*inv64, e[q*4+1]*inv64,
                               e[q*4+2]*inv64, e[q*4+3]*inv64);
        zb[q] = v;
        out[n*OUTC + q*4 + 0] = v.x;
        out[n*OUTC + q*4 + 1] = v.y;
        out[n*OUTC + q*4 + 2] = v.z;
        out[n*OUTC + q*4 + 3] = v.w;
    }
}

// ---------------- bin function ------------------------------------------
__device__ __forceinline__ int edge_bin(const float* __restrict__ pos,
                                        int src, int dst)
{
    float px = pos[dst*3+0] - pos[src*3+0];
    float py = pos[dst*3+1] - pos[src*3+1];
    float pz = pos[dst*3+2] - pos[src*3+2];
    float dist = sqrtf(px*px + py*py + pz*pz + 1e-12f);
    float tt = dist * 4.2f;
    if (!(tt < 21.0f)) return NBINS - 1;     // out-of-range bin
    int m = (int)tt;
    float gf = (tt - (float)m) * (float)TGRID;
    int g0 = (int)gf; if (g0 > TGRID-1) g0 = TGRID-1;
    return m * TGRID + g0;
}

// ---------------- count: LDS histogram + cache ebin ----------------------
__global__ __launch_bounds__(256) void count_bins_kernel(
    const int* __restrict__ ei, const float* __restrict__ pos,
    int* __restrict__ cd, int* __restrict__ cb, int* __restrict__ ebin)
{
    __shared__ int hist[NBINS];
    for (int b = threadIdx.x; b < NBINS; b += 256) hist[b] = 0;
    __syncthreads();

    int e = blockIdx.x * 256 + threadIdx.x;
    int s = ei[e];
    int d = ei[N_EDGES + e];
    int bin = edge_bin(pos, s, d);
    ebin[e] = bin;
    atomicAdd(&cd[d], 1);                    // 32k addresses: cheap
    atomicAdd(&hist[bin], 1);
    __syncthreads();

    for (int b = threadIdx.x; b < NBINS; b += 256) {
        int c = hist[b];
        if (c) atomicAdd(&cb[b], c);
    }
}

// dual scan: block 0 scans (c0,s0), block 1 scans (c1,s1). 32768 each.
__global__ __launch_bounds__(1024) void scan2_kernel(
    int* __restrict__ c0, int* __restrict__ s0arr,
    int* __restrict__ c1, int* __restrict__ s1arr)
{
    int* cursor = (blockIdx.x == 0) ? c0 : c1;
    int* start  = (blockIdx.x == 0) ? s0arr : s1arr;
    __shared__ int partial[1024];
    int tid = threadIdx.x;
    int base = tid * 32;
    int v[32];
    int s = 0;
    #pragma unroll
    for (int j = 0; j < 32; ++j) { v[j] = cursor[base + j]; s += v[j]; }
    partial[tid] = s;
    __syncthreads();
    for (int off = 1; off < 1024; off <<= 1) {
        int t = (tid >= off) ? partial[tid - off] : 0;
        __syncthreads();
        partial[tid] += t;
        __syncthreads();
    }
    int run = (tid > 0) ? partial[tid - 1] : 0;
    #pragma unroll
    for (int j = 0; j < 32; ++j) {
        start[base + j] = run;
        cursor[base + j] = run;
        run += v[j];
    }
    if (tid == 1023) start[32768] = run;
}

// ---------------- fill: two-level (LDS hist -> range reserve -> rank) -----
__global__ __launch_bounds__(256) void fill_bins_kernel(
    const int* __restrict__ ebin,
    int* __restrict__ cursor_bin,            // pre-scanned starts, consumed
    int* __restrict__ binlist, int* __restrict__ epos)
{
    __shared__ int hist[NBINS];
    __shared__ int rbase[NBINS];
    for (int b = threadIdx.x; b < NBINS; b += 256) hist[b] = 0;
    __syncthreads();

    int e = blockIdx.x * 256 + threadIdx.x;
    int bin = ebin[e];
    atomicAdd(&hist[bin], 1);
    __syncthreads();

    for (int b = threadIdx.x; b < NBINS; b += 256) {
        int c = hist[b];
        if (c) rbase[b] = atomicAdd(&cursor_bin[b], c);  // distinct addrs/wave
        hist[b] = 0;                                     // reuse as local cursor
    }
    __syncthreads();

    int lr = atomicAdd(&hist[bin], 1);       // LDS local rank
    int slot = rbase[bin] + lr;
    binlist[slot] = e;
    epos[e] = slot;
}

// ---------------- Table build: W_eff[m][g][i][c] ------------------------
__global__ __launch_bounds__(256) void table_kernel(
    const float* __restrict__ Wt1, const float* __restrict__ Wt2,
    float* __restrict__ T)
{
    int entry = blockIdx.x;            // 0 .. 21*65-1
    int m = entry / 65;
    int g = entry - m * 65;
    float d0 = (float)g * (1.0f / TGRID);
    float d1 = d0 - 1.0f;
    int j0 = m - 1, j1 = m;
    const float sq20 = 4.47213595499958f;

    float f0 = 0.f, f1 = 0.f;
    if (j0 >= 0 && j0 < 20)
        f0 = 1.14136f * expf(2.0f - 1.0f/(1.0f + d0) - 1.0f/(1.0f - d0)) * sq20;
    if (j1 >= 0 && j1 < 20)
        f1 = 1.14136f * expf(2.0f - 1.0f/(1.0f + d1) - 1.0f/(1.0f - d1)) * sq20;
    j0 = j0 < 0 ? 0 : (j0 > 19 ? 19 : j0);
    j1 = j1 < 0 ? 0 : (j1 > 19 ? 19 : j1);

    __shared__ float h[64];
    int t = threadIdx.x;
    if (t < 64) {
        float a = fmaf(f0, Wt1[j0*64 + t], f1 * Wt1[j1*64 + t])
                  * 0.22360679774997896f;
        h[t] = 1.679177f * a / (1.0f + expf(-a));
    }
    __syncthreads();

    // sc = 1/8 (w norm) * 1/4 (inv) * 1/sqrt(8) (neighbor norm)
    const float sc = 0.011048543456039806f;
    for (int e2 = t; e2 < TENT; e2 += 256) {
        int i = e2 / 24;
        int c = e2 - i * 24;
        float v = 0.f;
        if (c < 22) {
            int widx = (c < 16) ? (i*16 + c)
                     : (c < 20) ? (256 + i*4 + (c - 16))
                                : (320 + i*2 + (c - 20));
            for (int k = 0; k < 64; ++k)
                v = fmaf(h[k], Wt2[k*352 + widx], v);
            v *= sc;
        }
        T[(size_t)entry * TENT + e2] = v;
    }
}

// ---------------- Kernel 3: binned per-edge, fused lerp (low VGPR) --------
// Thread-per-edge; wave shares 1-2 table rows via binning -> broadcast
// loads. Fused lerp: single acc[24] (saves 24 VGPRs vs dual accumulators;
// identical math by linearity). fp16 tp row per thread (80 B, coalesced).
__global__ __launch_bounds__(256) void edge_table_binned(
    const float* __restrict__ pos, const int* __restrict__ ei,
    const float* __restrict__ T, const float* __restrict__ znode,
    const int* __restrict__ binlist,
    unsigned short* __restrict__ tp, int* __restrict__ cursor,
    int* __restrict__ elist)
{
    int idx = blockIdx.x * 256 + threadIdx.x;
    int e = binlist[idx];
    int src = ei[e];
    int dst = ei[N_EDGES + e];

    int slot = atomicAdd(&cursor[dst], 1);
    elist[slot] = e;

    uint4* d4 = (uint4*)(tp + (size_t)idx * TPW);   // binned layout

    float px = pos[dst*3+0] - pos[src*3+0];
    float py = pos[dst*3+1] - pos[src*3+1];
    float pz = pos[dst*3+2] - pos[src*3+2];
    float dist = sqrtf(px*px + py*py + pz*pz + 1e-12f);
    float rinv = 1.0f / dist;
    float ux = px*rinv, uy = py*rinv, uz = pz*rinv;

    float tt = dist * 4.2f;          // dist / (5/21)
    if (!(tt < 21.0f)) {             // out of radial range -> zero message
        uint4 z4 = make_uint4(0, 0, 0, 0);
        d4[0] = z4; d4[1] = z4; d4[2] = z4; d4[3] = z4; d4[4] = z4;
        return;
    }
    int m  = (int)tt;                // 0..20
    float d0 = tt - (float)m;
    float gf = d0 * (float)TGRID;
    int g0 = (int)gf; if (g0 > TGRID-1) g0 = TGRID-1;
    float fr = gf - (float)g0;

    const float4* r0 = (const float4*)(T + (size_t)(m*65 + g0) * TENT);
    const float4* r1 = r0 + (TENT/4);    // next d0 grid point (contiguous)

    // aligned vector z loads
    const float4* zp = (const float4*)(znode + (size_t)src * 16);
    float4 zq0 = zp[0], zq1 = zp[1], zq2 = zp[2], zq3 = zp[3];
    float z[16] = {zq0.x, zq0.y, zq0.z, zq0.w,
                   zq1.x, zq1.y, zq1.z, zq1.w,
                   zq2.x, zq2.y, zq2.z, zq2.w,
                   zq3.x, zq3.y, zq3.z, zq3.w};

    float acc[24];
    #pragma unroll
    for (int c = 0; c < 24; ++c) acc[c] = 0.f;

    #pragma unroll
    for (int i = 0; i < 16; ++i) {
        float zi = z[i];
        #pragma unroll
        for (int q = 0; q < 6; ++q) {
            float4 v0 = r0[i*6 + q];
            float4 v1 = r1[i*6 + q];
            float w;
            w = fmaf(fr, v1.x - v0.x, v0.x); acc[q*4+0] = fmaf(zi, w, acc[q*4+0]);
            w = fmaf(fr, v1.y - v0.y, v0.y); acc[q*4+1] = fmaf(zi, w, acc[q*4+1]);
            w = fmaf(fr, v1.z - v0.z, v0.z); acc[q*4+2] = fmaf(zi, w, acc[q*4+2]);
            w = fmaf(fr, v1.w - v0.w, v0.w); acc[q*4+3] = fmaf(zi, w, acc[q*4+3]);
        }
    }

    float vals[38];
    #pragma unroll
    for (int c = 0; c < 22; ++c) vals[c] = acc[c];

    const float s3  = 1.7320508075688772f;
    const float s15 = 3.872983346207417f;
    const float s5  = 2.23606797749979f;
    float sh1x = s3*ux, sh1y = s3*uy, sh1z = s3*uz;
    float sh2a = s15 * ux * uz;
    float sh2b = s15 * ux * uy;
    float sh2c = s5 * (uy*uy - 0.5f*(ux*ux + uz*uz));
    float sh2d = s15 * uy * uz;
    float sh2e = 0.5f * s15 * (uz*uz - ux*ux);

    // expand T first (consumes vals[20..21]), then V descending (16..19)
    #pragma unroll
    for (int u = 1; u >= 0; --u) {
        float v = vals[20 + u];
        vals[28 + u*5 + 0] = v * sh2a;
        vals[28 + u*5 + 1] = v * sh2b;
        vals[28 + u*5 + 2] = v * sh2c;
        vals[28 + u*5 + 3] = v * sh2d;
        vals[28 + u*5 + 4] = v * sh2e;
    }
    #pragma unroll
    for (int u = 3; u >= 0; --u) {
        float v = vals[16 + u];
        vals[16 + u*3 + 0] = v * sh1x;
        vals[16 + u*3 + 1] = v * sh1y;
        vals[16 + u*3 + 2] = v * sh1z;
    }

    // fp16 pack; store each uint4 immediately (short live ranges)
    d4[0] = make_uint4(pkh(vals[0], vals[1]),  pkh(vals[2], vals[3]),
                       pkh(vals[4], vals[5]),  pkh(vals[6], vals[7]));
    d4[1] = make_uint4(pkh(vals[8], vals[9]),  pkh(vals[10], vals[11]),
                       pkh(vals[12], vals[13]),pkh(vals[14], vals[15]));
    d4[2] = make_uint4(pkh(vals[16], vals[17]),pkh(vals[18], vals[19]),
                       pkh(vals[20], vals[21]),pkh(vals[22], vals[23]));
    d4[3] = make_uint4(pkh(vals[24], vals[25]),pkh(vals[26], vals[27]),
                       pkh(vals[28], vals[29]),pkh(vals[30], vals[31]));
    d4[4] = make_uint4(pkh(vals[32], vals[33]),pkh(vals[34], vals[35]),
                       pkh(vals[36], vals[37]),0);
}

// ---------------- Kernel 4: gather segment-sum, SORTED (deterministic) ------
// Packed reads: 19 lanes x 4B (2 halves) per row instead of 38 x 2B.
__global__ __launch_bounds__(256) void gather_sorted_kernel(
    const unsigned short* __restrict__ tp, const int* __restrict__ start,
    const int* __restrict__ elist, const int* __restrict__ epos,
    float* __restrict__ out)
{
    __shared__ int sb[4][128];
    __shared__ int so[4][128];
    int wave = threadIdx.x >> 6;
    int lane = threadIdx.x & 63;
    int n = blockIdx.x * 4 + wave;          // grid == N_NODES/4, always valid
    int s0 = start[n], s1 = start[n+1];
    int K = s1 - s0;
    bool small = (K <= 128);

    if (small) {
        for (int j = lane; j < K; j += 64) sb[wave][j] = elist[s0 + j];
    }
    __syncthreads();
    if (small) {
        for (int j = lane; j < K; j += 64) {
            int v = sb[wave][j];
            int r = 0;
            for (int q = 0; q < K; ++q) r += (sb[wave][q] < v);
            so[wave][r] = v;    // edge ids distinct -> r is a permutation
        }
    }
    __syncthreads();

    if (lane < 19) {
        float acc0 = 0.f, acc1 = 0.f;
        if (small) {
            for (int j = 0; j < K; ++j) {
                const unsigned* row = (const unsigned*)
                    (tp + (size_t)epos[so[wave][j]] * TPW);
                unsigned v = row[lane];
                acc0 += __half2float(__ushort_as_half((unsigned short)(v & 0xffffu)));
                acc1 += __half2float(__ushort_as_half((unsigned short)(v >> 16)));
            }
        } else {
            for (int j = s0; j < s1; ++j) {
                const unsigned* row = (const unsigned*)
                    (tp + (size_t)epos[elist[j]] * TPW);
                unsigned v = row[lane];
                acc0 += __half2float(__ushort_as_half((unsigned short)(v & 0xffffu)));
                acc1 += __half2float(__ushort_as_half((unsigned short)(v >> 16)));
            }
        }
        out[n*OUTC + 16 + 2*lane] = acc0;
        out[n*OUTC + 16 + 2*lane + 1] = acc1;
    }
}

// ---------------- fallback (atomics) if ws too small -----------------
__global__ __launch_bounds__(256) void edge_kernel_atomic(
    const float* __restrict__ pos, const int* __restrict__ ei,
    const float* __restrict__ Wt1, const float* __restrict__ Wt2,
    float* out)
{
    int e = blockIdx.x * blockDim.x + threadIdx.x;
    if (e >= N_EDGES) return;
    int src = ei[e];
    int dst = ei[N_EDGES + e];
    float px = pos[dst*3+0] - pos[src*3+0];
    float py = pos[dst*3+1] - pos[src*3+1];
    float pz = pos[dst*3+2] - pos[src*3+2];
    float dist = sqrtf(px*px + py*py + pz*pz + 1e-12f);
    float rinv = 1.0f / dist;
    float ux = px*rinv, uy = py*rinv, uz = pz*rinv;
    const float step = 5.0f / 21.0f;
    float tt = dist / step;
    int m  = (int)floorf(tt);
    int j0 = m - 1, j1 = m;
    float d0 = tt - (float)m, d1 = d0 - 1.0f;
    const float sq20 = 4.47213595499958f;
    float f0 = 0.f, f1 = 0.f;
    if (j0 >= 0 && j0 < 20)
        f0 = 1.14136f * expf(2.0f - 1.0f/(1.0f + d0) - 1.0f/(1.0f - d0)) * sq20;
    if (j1 >= 0 && j1 < 20 && d1 > -1.0f)
        f1 = 1.14136f * expf(2.0f - 1.0f/(1.0f + d1) - 1.0f/(1.0f - d1)) * sq20;
    if (f0 == 0.f && f1 == 0.f) return;
    j0 = j0 < 0 ? 0 : (j0 > 19 ? 19 : j0);
    j1 = j1 < 0 ? 0 : (j1 > 19 ? 19 : j1);
    const float* w1a = Wt1 + j0*64;
    const float* w1b = Wt1 + j1*64;
    float z[16];
    #pragma unroll
    for (int i = 0; i < 16; ++i) z[i] = out[src*OUTC + i];
    const float rsq20 = 0.22360679774997896f;
    const float snorm = 1.679177f;
    float accS[16], accV[4], accT[2];
    #pragma unroll
    for (int u = 0; u < 16; ++u) accS[u] = 0.f;
    #pragma unroll
    for (int u = 0; u < 4; ++u) accV[u] = 0.f;
    #pragma unroll
    for (int u = 0; u < 2; ++u) accT[u] = 0.f;
    for (int k = 0; k < 64; ++k) {
        float a = fmaf(f0, w1a[k], f1 * w1b[k]) * rsq20;
        float hk = snorm * a / (1.0f + expf(-a));
        const float* row = Wt2 + k*352;
        float tmp[16];
        #pragma unroll
        for (int u = 0; u < 16; ++u) tmp[u] = 0.f;
        #pragma unroll
        for (int i = 0; i < 16; ++i) {
            float zi = z[i];
            #pragma unroll
            for (int u = 0; u < 16; ++u) tmp[u] = fmaf(zi, row[i*16 + u], tmp[u]);
        }
        #pragma unroll
        for (int u = 0; u < 16; ++u) accS[u] = fmaf(hk, tmp[u], accS[u]);
        float tv[4] = {0.f,0.f,0.f,0.f};
        #pragma unroll
        for (int i = 0; i < 16; ++i) {
            float zi = z[i];
            #pragma unroll
            for (int u = 0; u < 4; ++u) tv[u] = fmaf(zi, row[256 + i*4 + u], tv[u]);
        }
        #pragma unroll
        for (int u = 0; u < 4; ++u) accV[u] = fmaf(hk, tv[u], accV[u]);
        float tw[2] = {0.f,0.f};
        #pragma unroll
        for (int i = 0; i < 16; ++i) {
            float zi = z[i];
            #pragma unroll
            for (int u = 0; u < 2; ++u) tw[u] = fmaf(zi, row[320 + i*2 + u], tw[u]);
        }
        #pragma unroll
        for (int u = 0; u < 2; ++u) accT[u] = fmaf(hk, tw[u], accT[u]);
    }
    const float sc = 0.125f * 0.25f * 0.35355339059327373f;
    const float s3  = 1.7320508075688772f;
    const float s15 = 3.872983346207417f;
    const float s5  = 2.23606797749979f;
    float sh1x = s3*ux, sh1y = s3*uy, sh1z = s3*uz;
    float sh2[5];
    sh2[0] = s15 * ux * uz;
    sh2[1] = s15 * ux * uy;
    sh2[2] = s5 * (uy*uy - 0.5f*(ux*ux + uz*uz));
    sh2[3] = s15 * uy * uz;
    sh2[4] = 0.5f * s15 * (uz*uz - ux*ux);
    float* orow = out + dst*OUTC + 16;
    #pragma unroll
    for (int u = 0; u < 16; ++u) atomicAdd(&orow[u], accS[u] * sc);
    #pragma unroll
    for (int u = 0; u < 4; ++u) {
        float v = accV[u] * sc;
        atomicAdd(&orow[16 + u*3 + 0], v * sh1x);
        atomicAdd(&orow[16 + u*3 + 1], v * sh1y);
        atomicAdd(&orow[16 + u*3 + 2], v * sh1z);
    }
    #pragma unroll
    for (int u = 0; u < 2; ++u) {
        float v = accT[u] * sc;
        #pragma unroll
        for (int mm = 0; mm < 5; ++mm)
            atomicAdd(&orow[28 + u*5 + mm], v * sh2[mm]);
    }
}

extern "C" void kernel_launch(void* const* d_in, const int* in_sizes, int n_in,
                              void* d_out, int out_size, void* d_ws, size_t ws_size,
                              hipStream_t stream) {
    const float* x   = (const float*)d_in[0];
    const float* pos = (const float*)d_in[1];
    const int*   ei  = (const int*)d_in[2];
    const float* We1 = (const float*)d_in[3];
    const float* We2 = (const float*)d_in[4];
    const float* Wt1 = (const float*)d_in[5];
    const float* Wt2 = (const float*)d_in[6];
    float* out = (float*)d_out;

    char* base = (char*)d_ws;
    size_t off = 0;
    unsigned short* tp = (unsigned short*)(base + off);
    off += (size_t)N_EDGES * TPW * 2;                    // fp16 rows, 21 MB
    float* T  = (float*)(base + off);       off += (size_t)21 * 65 * TENT * 4;  // 2.1 MB
    float* znode = (float*)(base + off);    off += (size_t)N_NODES * 16 * 4;    // 2 MB
    int* cursor_dst = (int*)(base + off);   off += (size_t)32768 * 4;
    int* cursor_bin = (int*)(base + off);   off += (size_t)32768 * 4;   // adjacent: one memset
    int* start_dst  = (int*)(base + off);   off += (size_t)32769 * 4;
    int* start_bin  = (int*)(base + off);   off += (size_t)32769 * 4;
    int* elist   = (int*)(base + off);      off += (size_t)N_EDGES * 4;
    int* binlist = (int*)(base + off);      off += (size_t)N_EDGES * 4;
    int* epos    = (int*)(base + off);      off += (size_t)N_EDGES * 4;
    int* ebin    = (int*)(base + off);      off += (size_t)N_EDGES * 4;
    size_t need = off;

    if (ws_size >= need) {
        node_emb_kernel<<<N_NODES/256, 256, 0, stream>>>(x, We1, We2, out, znode);
        table_kernel<<<21*65, 256, 0, stream>>>(Wt1, Wt2, T);
        hipMemsetAsync(cursor_dst, 0, (size_t)2 * 32768 * 4, stream);
        count_bins_kernel<<<N_EDGES/256, 256, 0, stream>>>(ei, pos, cursor_dst,
                                                           cursor_bin, ebin);
        scan2_kernel<<<2, 1024, 0, stream>>>(cursor_dst, start_dst,
                                             cursor_bin, start_bin);
        fill_bins_kernel<<<N_EDGES/256, 256, 0, stream>>>(ebin, cursor_bin,
                                                          binlist, epos);
        edge_table_binned<<<N_EDGES/256, 256, 0, stream>>>(pos, ei, T, znode,
                                                           binlist, tp,
                                                           cursor_dst, elist);
        gather_sorted_kernel<<<N_NODES/4, 256, 0, stream>>>(tp, start_dst,
                                                            elist, epos, out);
    } else {
        hipMemsetAsync(out, 0, (size_t)out_size * sizeof(float), stream);
        node_emb_kernel<<<N_NODES/256, 256, 0, stream>>>(x, We1, We2, out,
                                                         (float*)d_ws);
        edge_kernel_atomic<<<N_EDGES/256, 256, 0, stream>>>(pos, ei, Wt1, Wt2, out);
    }
}

// Round 18
// 176.859 us; speedup vs baseline: 1.5695x; 1.1554x over previous
//
#include <hip/hip_runtime.h>
#include <hip/hip_fp16.h>
#include <math.h>

#define N_NODES 32768
#define N_EDGES 262144
#define OUTC 54      // 16 emb + 38 msg
#define TPW  40      // tp row stride in HALVES (38 used, 80 B, 16B-aligned)
#define TGRID 64     // d0 samples per bin (65 points incl. both ends)
#define TENT 384     // floats per table entry: 16 i * 24 padded cols
#define NBINS 1345   // 21*64 in-range bins + 1 out-of-range bin
#define TBLOCKS 1365 // 21*65 table entries

__device__ __forceinline__ unsigned pkh(float a, float b) {
    auto r = __builtin_amdgcn_cvt_pkrtz(a, b);   // v_cvt_pkrtz_f16_f32
    union { decltype(r) v; unsigned u; } cv;
    cv.v = r;
    return cv.u;
}

// ---------------- Kernel 1: node embeddings (+ aligned z copy) -----------
__global__ __launch_bounds__(256) void node_emb_kernel(
    const float* __restrict__ x, const float* __restrict__ W1,
    const float* __restrict__ W2, float* __restrict__ out,
    float* __restrict__ znode)
{
    int n = blockIdx.x * blockDim.x + threadIdx.x;
    if (n >= N_NODES) return;
    const float inv10 = 0.31622776601683794f;
    const float inv64 = 0.125f;

    float xr[10];
    #pragma unroll
    for (int i = 0; i < 10; ++i) xr[i] = x[n*10 + i];

    float t[64];
    #pragma unroll
    for (int k = 0; k < 64; ++k) {
        float acc = 0.f;
        #pragma unroll
        for (int i = 0; i < 10; ++i) acc = fmaf(xr[i], W1[i*64 + k], acc);
        t[k] = acc * inv10;
    }

    float e[16];
    #pragma unroll
    for (int j = 0; j < 16; ++j) e[j] = 0.f;
    #pragma unroll
    for (int k = 0; k < 64; ++k) {
        float tk = t[k];
        #pragma unroll
        for (int j = 0; j < 16; ++j) e[j] = fmaf(tk, W2[k*16 + j], e[j]);
    }
    float4* zb = (float4*)(znode + (size_t)n * 16);
    #pragma unroll
    for (int q = 0; q < 4; ++q) {
        float4 v = make_float4(e[q*4+0]*inv64, e[q*4+1]*inv64,
                               e[q*4+2]*inv64, e[q*4+3]*inv64);
        zb[q] = v;
        out[n*OUTC + q*4 + 0] = v.x;
        out[n*OUTC + q*4 + 1] = v.y;
        out[n*OUTC + q*4 + 2] = v.z;
        out[n*OUTC + q*4 + 3] = v.w;
    }
}

// ---------------- bin function ------------------------------------------
__device__ __forceinline__ int edge_bin(const float* __restrict__ pos,
                                        int src, int dst)
{
    float px = pos[dst*3+0] - pos[src*3+0];
    float py = pos[dst*3+1] - pos[src*3+1];
    float pz = pos[dst*3+2] - pos[src*3+2];
    float dist = sqrtf(px*px + py*py + pz*pz + 1e-12f);
    float tt = dist * 4.2f;
    if (!(tt < 21.0f)) return NBINS - 1;     // out-of-range bin
    int m = (int)tt;
    float gf = (tt - (float)m) * (float)TGRID;
    int g0 = (int)gf; if (g0 > TGRID-1) g0 = TGRID-1;
    return m * TGRID + g0;
}

// ---------------- prep: fused table-build (blocks 0..1364) ---------------
//                  + bin/dst count (blocks 1365..2388) ---------------------
// The two parts are independent; fusing lets them overlap on the CUs
// instead of serializing as two launches.
__global__ __launch_bounds__(256) void prep_kernel(
    const float* __restrict__ Wt1, const float* __restrict__ Wt2,
    float* __restrict__ T,
    const int* __restrict__ ei, const float* __restrict__ pos,
    int* __restrict__ cd, int* __restrict__ cb, int* __restrict__ ebin)
{
    __shared__ int hist[NBINS];
    __shared__ float h[64];
    int t = threadIdx.x;

    if (blockIdx.x < TBLOCKS) {
        // ---- table part ----
        int entry = blockIdx.x;            // 0 .. 21*65-1
        int m = entry / 65;
        int g = entry - m * 65;
        float d0 = (float)g * (1.0f / TGRID);
        float d1 = d0 - 1.0f;
        int j0 = m - 1, j1 = m;
        const float sq20 = 4.47213595499958f;

        float f0 = 0.f, f1 = 0.f;
        if (j0 >= 0 && j0 < 20)
            f0 = 1.14136f * expf(2.0f - 1.0f/(1.0f + d0) - 1.0f/(1.0f - d0)) * sq20;
        if (j1 >= 0 && j1 < 20)
            f1 = 1.14136f * expf(2.0f - 1.0f/(1.0f + d1) - 1.0f/(1.0f - d1)) * sq20;
        j0 = j0 < 0 ? 0 : (j0 > 19 ? 19 : j0);
        j1 = j1 < 0 ? 0 : (j1 > 19 ? 19 : j1);

        if (t < 64) {
            float a = fmaf(f0, Wt1[j0*64 + t], f1 * Wt1[j1*64 + t])
                      * 0.22360679774997896f;
            h[t] = 1.679177f * a / (1.0f + expf(-a));
        }
        __syncthreads();

        const float sc = 0.011048543456039806f;
        for (int e2 = t; e2 < TENT; e2 += 256) {
            int i = e2 / 24;
            int c = e2 - i * 24;
            float v = 0.f;
            if (c < 22) {
                int widx = (c < 16) ? (i*16 + c)
                         : (c < 20) ? (256 + i*4 + (c - 16))
                                    : (320 + i*2 + (c - 20));
                for (int k = 0; k < 64; ++k)
                    v = fmaf(h[k], Wt2[k*352 + widx], v);
                v *= sc;
            }
            T[(size_t)entry * TENT + e2] = v;
        }
    } else {
        // ---- count part ----
        for (int b = t; b < NBINS; b += 256) hist[b] = 0;
        __syncthreads();

        int e = (blockIdx.x - TBLOCKS) * 256 + t;
        int s = ei[e];
        int d = ei[N_EDGES + e];
        int bin = edge_bin(pos, s, d);
        ebin[e] = bin;
        atomicAdd(&cd[d], 1);                // 32k addresses: cheap
        atomicAdd(&hist[bin], 1);
        __syncthreads();

        for (int b = t; b < NBINS; b += 256) {
            int c = hist[b];
            if (c) atomicAdd(&cb[b], c);
        }
    }
}

// dual scan: block 0 scans (c0,s0), block 1 scans (c1,s1). 32768 each.
__global__ __launch_bounds__(1024) void scan2_kernel(
    int* __restrict__ c0, int* __restrict__ s0arr,
    int* __restrict__ c1, int* __restrict__ s1arr)
{
    int* cursor = (blockIdx.x == 0) ? c0 : c1;
    int* start  = (blockIdx.x == 0) ? s0arr : s1arr;
    __shared__ int partial[1024];
    int tid = threadIdx.x;
    int base = tid * 32;
    int v[32];
    int s = 0;
    #pragma unroll
    for (int j = 0; j < 32; ++j) { v[j] = cursor[base + j]; s += v[j]; }
    partial[tid] = s;
    __syncthreads();
    for (int off = 1; off < 1024; off <<= 1) {
        int t = (tid >= off) ? partial[tid - off] : 0;
        __syncthreads();
        partial[tid] += t;
        __syncthreads();
    }
    int run = (tid > 0) ? partial[tid - 1] : 0;
    #pragma unroll
    for (int j = 0; j < 32; ++j) {
        start[base + j] = run;
        cursor[base + j] = run;
        run += v[j];
    }
    if (tid == 1023) start[32768] = run;
}

// ---------------- fill: two-level; emits int4 {e, src, dst, 0} ------------
// Packing src/dst into the slot record removes one dependent-load level
// from the edge kernel's critical path (binlist -> ei -> pos/znode).
__global__ __launch_bounds__(256) void fill_bins_kernel(
    const int* __restrict__ ebin, const int* __restrict__ ei,
    int* __restrict__ cursor_bin,            // pre-scanned starts, consumed
    int4* __restrict__ binfo)
{
    __shared__ int hist[NBINS];
    __shared__ int rbase[NBINS];
    for (int b = threadIdx.x; b < NBINS; b += 256) hist[b] = 0;
    __syncthreads();

    int e = blockIdx.x * 256 + threadIdx.x;
    int bin = ebin[e];
    atomicAdd(&hist[bin], 1);
    __syncthreads();

    for (int b = threadIdx.x; b < NBINS; b += 256) {
        int c = hist[b];
        if (c) rbase[b] = atomicAdd(&cursor_bin[b], c);  // distinct addrs/wave
        hist[b] = 0;                                     // reuse as local cursor
    }
    __syncthreads();

    int lr = atomicAdd(&hist[bin], 1);       // LDS local rank
    int slot = rbase[bin] + lr;
    binfo[slot] = make_int4(e, ei[e], ei[N_EDGES + e], 0);
}

// ---------------- Kernel 3: binned per-edge, fused lerp -------------------
// Thread-per-edge; wave shares 1-2 table rows via binning. Emits
// int2 {edge_id, tp_row} into the dst slot so the gather needs no epos.
__global__ __launch_bounds__(256) void edge_table_binned(
    const float* __restrict__ pos,
    const float* __restrict__ T, const float* __restrict__ znode,
    const int4* __restrict__ binfo,
    unsigned short* __restrict__ tp, int* __restrict__ cursor,
    int2* __restrict__ elist2)
{
    int idx = blockIdx.x * 256 + threadIdx.x;
    int4 bf = binfo[idx];
    int e   = bf.x;
    int src = bf.y;
    int dst = bf.z;

    int slot = atomicAdd(&cursor[dst], 1);
    elist2[slot] = make_int2(e, idx);

    uint4* d4 = (uint4*)(tp + (size_t)idx * TPW);   // binned layout

    float px = pos[dst*3+0] - pos[src*3+0];
    float py = pos[dst*3+1] - pos[src*3+1];
    float pz = pos[dst*3+2] - pos[src*3+2];
    float dist = sqrtf(px*px + py*py + pz*pz + 1e-12f);
    float rinv = 1.0f / dist;
    float ux = px*rinv, uy = py*rinv, uz = pz*rinv;

    float tt = dist * 4.2f;          // dist / (5/21)
    if (!(tt < 21.0f)) {             // out of radial range -> zero message
        uint4 z4 = make_uint4(0, 0, 0, 0);
        d4[0] = z4; d4[1] = z4; d4[2] = z4; d4[3] = z4; d4[4] = z4;
        return;
    }
    int m  = (int)tt;                // 0..20
    float d0 = tt - (float)m;
    float gf = d0 * (float)TGRID;
    int g0 = (int)gf; if (g0 > TGRID-1) g0 = TGRID-1;
    float fr = gf - (float)g0;

    const float4* r0 = (const float4*)(T + (size_t)(m*65 + g0) * TENT);
    const float4* r1 = r0 + (TENT/4);    // next d0 grid point (contiguous)

    // aligned vector z loads
    const float4* zp = (const float4*)(znode + (size_t)src * 16);
    float4 zq0 = zp[0], zq1 = zp[1], zq2 = zp[2], zq3 = zp[3];
    float z[16] = {zq0.x, zq0.y, zq0.z, zq0.w,
                   zq1.x, zq1.y, zq1.z, zq1.w,
                   zq2.x, zq2.y, zq2.z, zq2.w,
                   zq3.x, zq3.y, zq3.z, zq3.w};

    float acc[24];
    #pragma unroll
    for (int c = 0; c < 24; ++c) acc[c] = 0.f;

    #pragma unroll
    for (int i = 0; i < 16; ++i) {
        float zi = z[i];
        #pragma unroll
        for (int q = 0; q < 6; ++q) {
            float4 v0 = r0[i*6 + q];
            float4 v1 = r1[i*6 + q];
            float w;
            w = fmaf(fr, v1.x - v0.x, v0.x); acc[q*4+0] = fmaf(zi, w, acc[q*4+0]);
            w = fmaf(fr, v1.y - v0.y, v0.y); acc[q*4+1] = fmaf(zi, w, acc[q*4+1]);
            w = fmaf(fr, v1.z - v0.z, v0.z); acc[q*4+2] = fmaf(zi, w, acc[q*4+2]);
            w = fmaf(fr, v1.w - v0.w, v0.w); acc[q*4+3] = fmaf(zi, w, acc[q*4+3]);
        }
    }

    float vals[38];
    #pragma unroll
    for (int c = 0; c < 22; ++c) vals[c] = acc[c];

    const float s3  = 1.7320508075688772f;
    const float s15 = 3.872983346207417f;
    const float s5  = 2.23606797749979f;
    float sh1x = s3*ux, sh1y = s3*uy, sh1z = s3*uz;
    float sh2a = s15 * ux * uz;
    float sh2b = s15 * ux * uy;
    float sh2c = s5 * (uy*uy - 0.5f*(ux*ux + uz*uz));
    float sh2d = s15 * uy * uz;
    float sh2e = 0.5f * s15 * (uz*uz - ux*ux);

    // expand T first (consumes vals[20..21]), then V descending (16..19)
    #pragma unroll
    for (int u = 1; u >= 0; --u) {
        float v = vals[20 + u];
        vals[28 + u*5 + 0] = v * sh2a;
        vals[28 + u*5 + 1] = v * sh2b;
        vals[28 + u*5 + 2] = v * sh2c;
        vals[28 + u*5 + 3] = v * sh2d;
        vals[28 + u*5 + 4] = v * sh2e;
    }
    #pragma unroll
    for (int u = 3; u >= 0; --u) {
        float v = vals[16 + u];
        vals[16 + u*3 + 0] = v * sh1x;
        vals[16 + u*3 + 1] = v * sh1y;
        vals[16 + u*3 + 2] = v * sh1z;
    }

    // fp16 pack; store each uint4 immediately (short live ranges)
    d4[0] = make_uint4(pkh(vals[0], vals[1]),  pkh(vals[2], vals[3]),
                       pkh(vals[4], vals[5]),  pkh(vals[6], vals[7]));
    d4[1] = make_uint4(pkh(vals[8], vals[9]),  pkh(vals[10], vals[11]),
                       pkh(vals[12], vals[13]),pkh(vals[14], vals[15]));
    d4[2] = make_uint4(pkh(vals[16], vals[17]),pkh(vals[18], vals[19]),
                       pkh(vals[20], vals[21]),pkh(vals[22], vals[23]));
    d4[3] = make_uint4(pkh(vals[24], vals[25]),pkh(vals[26], vals[27]),
                       pkh(vals[28], vals[29]),pkh(vals[30], vals[31]));
    d4[4] = make_uint4(pkh(vals[32], vals[33]),pkh(vals[34], vals[35]),
                       pkh(vals[36], vals[37]),0);
}

// ---------------- Kernel 4: gather segment-sum, SORTED (deterministic) ------
// elist2 holds {edge_id, tp_row}: rank-sort by edge id (order-invariant sum)
// and read the row directly — no epos indirection.
__global__ __launch_bounds__(256) void gather_sorted_kernel(
    const unsigned short* __restrict__ tp, const int* __restrict__ start,
    const int2* __restrict__ elist2, float* __restrict__ out)
{
    __shared__ int sid[4][128];
    __shared__ int srw[4][128];
    __shared__ int so[4][128];
    int wave = threadIdx.x >> 6;
    int lane = threadIdx.x & 63;
    int n = blockIdx.x * 4 + wave;          // grid == N_NODES/4, always valid
    int s0 = start[n], s1 = start[n+1];
    int K = s1 - s0;
    bool small = (K <= 128);

    if (small) {
        for (int j = lane; j < K; j += 64) {
            int2 v = elist2[s0 + j];
            sid[wave][j] = v.x;
            srw[wave][j] = v.y;
        }
    }
    __syncthreads();
    if (small) {
        for (int j = lane; j < K; j += 64) {
            int v = sid[wave][j];
            int r = 0;
            for (int q = 0; q < K; ++q) r += (sid[wave][q] < v);
            so[wave][r] = srw[wave][j];   // edge ids distinct -> permutation
        }
    }
    __syncthreads();

    if (lane < 19) {
        float acc0 = 0.f, acc1 = 0.f;
        if (small) {
            for (int j = 0; j < K; ++j) {
                const unsigned* row = (const unsigned*)
                    (tp + (size_t)so[wave][j] * TPW);
                unsigned v = row[lane];
                acc0 += __half2float(__ushort_as_half((unsigned short)(v & 0xffffu)));
                acc1 += __half2float(__ushort_as_half((unsigned short)(v >> 16)));
            }
        } else {
            for (int j = s0; j < s1; ++j) {
                int2 ev = elist2[j];
                const unsigned* row = (const unsigned*)
                    (tp + (size_t)ev.y * TPW);
                unsigned v = row[lane];
                acc0 += __half2float(__ushort_as_half((unsigned short)(v & 0xffffu)));
                acc1 += __half2float(__ushort_as_half((unsigned short)(v >> 16)));
            }
        }
        out[n*OUTC + 16 + 2*lane] = acc0;
        out[n*OUTC + 16 + 2*lane + 1] = acc1;
    }
}

// ---------------- fallback (atomics) if ws too small -----------------
__global__ __launch_bounds__(256) void edge_kernel_atomic(
    const float* __restrict__ pos, const int* __restrict__ ei,
    const float* __restrict__ Wt1, const float* __restrict__ Wt2,
    float* out)
{
    int e = blockIdx.x * blockDim.x + threadIdx.x;
    if (e >= N_EDGES) return;
    int src = ei[e];
    int dst = ei[N_EDGES + e];
    float px = pos[dst*3+0] - pos[src*3+0];
    float py = pos[dst*3+1] - pos[src*3+1];
    float pz = pos[dst*3+2] - pos[src*3+2];
    float dist = sqrtf(px*px + py*py + pz*pz + 1e-12f);
    float rinv = 1.0f / dist;
    float ux = px*rinv, uy = py*rinv, uz = pz*rinv;
    const float step = 5.0f / 21.0f;
    float tt = dist / step;
    int m  = (int)floorf(tt);
    int j0 = m - 1, j1 = m;
    float d0 = tt - (float)m, d1 = d0 - 1.0f;
    const float sq20 = 4.47213595499958f;
    float f0 = 0.f, f1 = 0.f;
    if (j0 >= 0 && j0 < 20)
        f0 = 1.14136f * expf(2.0f - 1.0f/(1.0f + d0) - 1.0f/(1.0f - d0)) * sq20;
    if (j1 >= 0 && j1 < 20 && d1 > -1.0f)
        f1 = 1.14136f * expf(2.0f - 1.0f/(1.0f + d1) - 1.0f/(1.0f - d1)) * sq20;
    if (f0 == 0.f && f1 == 0.f) return;
    j0 = j0 < 0 ? 0 : (j0 > 19 ? 19 : j0);
    j1 = j1 < 0 ? 0 : (j1 > 19 ? 19 : j1);
    const float* w1a = Wt1 + j0*64;
    const float* w1b = Wt1 + j1*64;
    float z[16];
    #pragma unroll
    for (int i = 0; i < 16; ++i) z[i] = out[src*OUTC + i];
    const float rsq20 = 0.22360679774997896f;
    const float snorm = 1.679177f;
    float accS[16], accV[4], accT[2];
    #pragma unroll
    for (int u = 0; u < 16; ++u) accS[u] = 0.f;
    #pragma unroll
    for (int u = 0; u < 4; ++u) accV[u] = 0.f;
    #pragma unroll
    for (int u = 0; u < 2; ++u) accT[u] = 0.f;
    for (int k = 0; k < 64; ++k) {
        float a = fmaf(f0, w1a[k], f1 * w1b[k]) * rsq20;
        float hk = snorm * a / (1.0f + expf(-a));
        const float* row = Wt2 + k*352;
        float tmp[16];
        #pragma unroll
        for (int u = 0; u < 16; ++u) tmp[u] = 0.f;
        #pragma unroll
        for (int i = 0; i < 16; ++i) {
            float zi = z[i];
            #pragma unroll
            for (int u = 0; u < 16; ++u) tmp[u] = fmaf(zi, row[i*16 + u], tmp[u]);
        }
        #pragma unroll
        for (int u = 0; u < 16; ++u) accS[u] = fmaf(hk, tmp[u], accS[u]);
        float tv[4] = {0.f,0.f,0.f,0.f};
        #pragma unroll
        for (int i = 0; i < 16; ++i) {
            float zi = z[i];
            #pragma unroll
            for (int u = 0; u < 4; ++u) tv[u] = fmaf(zi, row[256 + i*4 + u], tv[u]);
        }
        #pragma unroll
        for (int u = 0; u < 4; ++u) accV[u] = fmaf(hk, tv[u], accV[u]);
        float tw[2] = {0.f,0.f};
        #pragma unroll
        for (int i = 0; i < 16; ++i) {
            float zi = z[i];
            #pragma unroll
            for (int u = 0; u < 2; ++u) tw[u] = fmaf(zi, row[320 + i*2 + u], tw[u]);
        }
        #pragma unroll
        for (int u = 0; u < 2; ++u) accT[u] = fmaf(hk, tw[u], accT[u]);
    }
    const float sc = 0.125f * 0.25f * 0.35355339059327373f;
    const float s3  = 1.7320508075688772f;
    const float s15 = 3.872983346207417f;
    const float s5  = 2.23606797749979f;
    float sh1x = s3*ux, sh1y = s3*uy, sh1z = s3*uz;
    float sh2[5];
    sh2[0] = s15 * ux * uz;
    sh2[1] = s15 * ux * uy;
    sh2[2] = s5 * (uy*uy - 0.5f*(ux*ux + uz*uz));
    sh2[3] = s15 * uy * uz;
    sh2[4] = 0.5f * s15 * (uz*uz - ux*ux);
    float* orow = out + dst*OUTC + 16;
    #pragma unroll
    for (int u = 0; u < 16; ++u) atomicAdd(&orow[u], accS[u] * sc);
    #pragma unroll
    for (int u = 0; u < 4; ++u) {
        float v = accV[u] * sc;
        atomicAdd(&orow[16 + u*3 + 0], v * sh1x);
        atomicAdd(&orow[16 + u*3 + 1], v * sh1y);
        atomicAdd(&orow[16 + u*3 + 2], v * sh1z);
    }
    #pragma unroll
    for (int u = 0; u < 2; ++u) {
        float v = accT[u] * sc;
        #pragma unroll
        for (int mm = 0; mm < 5; ++mm)
            atomicAdd(&orow[28 + u*5 + mm], v * sh2[mm]);
    }
}

extern "C" void kernel_launch(void* const* d_in, const int* in_sizes, int n_in,
                              void* d_out, int out_size, void* d_ws, size_t ws_size,
                              hipStream_t stream) {
    const float* x   = (const float*)d_in[0];
    const float* pos = (const float*)d_in[1];
    const int*   ei  = (const int*)d_in[2];
    const float* We1 = (const float*)d_in[3];
    const float* We2 = (const float*)d_in[4];
    const float* Wt1 = (const float*)d_in[5];
    const float* Wt2 = (const float*)d_in[6];
    float* out = (float*)d_out;

    char* base = (char*)d_ws;
    size_t off = 0;
    unsigned short* tp = (unsigned short*)(base + off);
    off += (size_t)N_EDGES * TPW * 2;                    // fp16 rows, 21 MB
    float* T  = (float*)(base + off);       off += (size_t)TBLOCKS * TENT * 4;  // 2.1 MB
    float* znode = (float*)(base + off);    off += (size_t)N_NODES * 16 * 4;    // 2 MB
    int* cursor_dst = (int*)(base + off);   off += (size_t)32768 * 4;
    int* cursor_bin = (int*)(base + off);   off += (size_t)32768 * 4;   // adjacent: one memset
    int* start_dst  = (int*)(base + off);   off += (size_t)32769 * 4;
    int* start_bin  = (int*)(base + off);   off += (size_t)32769 * 4;
    int* ebin       = (int*)(base + off);   off += (size_t)N_EDGES * 4;
    int4* binfo     = (int4*)(base + off);  off += (size_t)N_EDGES * 16;
    int2* elist2    = (int2*)(base + off);  off += (size_t)N_EDGES * 8;
    size_t need = off;

    if (ws_size >= need) {
        node_emb_kernel<<<N_NODES/256, 256, 0, stream>>>(x, We1, We2, out, znode);
        hipMemsetAsync(cursor_dst, 0, (size_t)2 * 32768 * 4, stream);
        prep_kernel<<<TBLOCKS + N_EDGES/256, 256, 0, stream>>>(
            Wt1, Wt2, T, ei, pos, cursor_dst, cursor_bin, ebin);
        scan2_kernel<<<2, 1024, 0, stream>>>(cursor_dst, start_dst,
                                             cursor_bin, start_bin);
        fill_bins_kernel<<<N_EDGES/256, 256, 0, stream>>>(ebin, ei, cursor_bin,
                                                          binfo);
        edge_table_binned<<<N_EDGES/256, 256, 0, stream>>>(pos, T, znode,
                                                           binfo, tp,
                                                           cursor_dst, elist2);
        gather_sorted_kernel<<<N_NODES/4, 256, 0, stream>>>(tp, start_dst,
                                                            elist2, out);
    } else {
        hipMemsetAsync(out, 0, (size_t)out_size * sizeof(float), stream);
        node_emb_kernel<<<N_NODES/256, 256, 0, stream>>>(x, We1, We2, out,
                                                         (float*)d_ws);
        edge_kernel_atomic<<<N_EDGES/256, 256, 0, stream>>>(pos, ei, Wt1, Wt2, out);
    }
}

// Round 19
// 174.827 us; speedup vs baseline: 1.5877x; 1.0116x over previous
//
#include <hip/hip_runtime.h>
#include <hip/hip_fp16.h>
#include <math.h>

#define N_NODES 32768
#define N_EDGES 262144
#define OUTC 54      // 16 emb + 38 msg
#define TPW  40      // tp row stride in HALVES (38 used, 80 B, 16B-aligned)
#define TGRID 64     // d0 samples per bin (65 points incl. both ends)
#define TENT 384     // floats per table entry: 16 i * 24 padded cols
#define NBINS 1345   // 21*64 in-range bins + 1 out-of-range bin
#define TBLOCKS 1365 // 21*65 table entries

__device__ __forceinline__ unsigned pkh(float a, float b) {
    auto r = __builtin_amdgcn_cvt_pkrtz(a, b);   // v_cvt_pkrtz_f16_f32
    union { decltype(r) v; unsigned u; } cv;
    cv.v = r;
    return cv.u;
}

// ---------------- Kernel 1: node embeddings (+ aligned z copy) -----------
__global__ __launch_bounds__(256) void node_emb_kernel(
    const float* __restrict__ x, const float* __restrict__ W1,
    const float* __restrict__ W2, float* __restrict__ out,
    float* __restrict__ znode)
{
    int n = blockIdx.x * blockDim.x + threadIdx.x;
    if (n >= N_NODES) return;
    const float inv10 = 0.31622776601683794f;
    const float inv64 = 0.125f;

    float xr[10];
    #pragma unroll
    for (int i = 0; i < 10; ++i) xr[i] = x[n*10 + i];

    float t[64];
    #pragma unroll
    for (int k = 0; k < 64; ++k) {
        float acc = 0.f;
        #pragma unroll
        for (int i = 0; i < 10; ++i) acc = fmaf(xr[i], W1[i*64 + k], acc);
        t[k] = acc * inv10;
    }

    float e[16];
    #pragma unroll
    for (int j = 0; j < 16; ++j) e[j] = 0.f;
    #pragma unroll
    for (int k = 0; k < 64; ++k) {
        float tk = t[k];
        #pragma unroll
        for (int j = 0; j < 16; ++j) e[j] = fmaf(tk, W2[k*16 + j], e[j]);
    }
    float4* zb = (float4*)(znode + (size_t)n * 16);
    #pragma unroll
    for (int q = 0; q < 4; ++q) {
        float4 v = make_float4(e[q*4+0]*inv64, e[q*4+1]*inv64,
                               e[q*4+2]*inv64, e[q*4+3]*inv64);
        zb[q] = v;
        out[n*OUTC + q*4 + 0] = v.x;
        out[n*OUTC + q*4 + 1] = v.y;
        out[n*OUTC + q*4 + 2] = v.z;
        out[n*OUTC + q*4 + 3] = v.w;
    }
}

// ---------------- prep: fused table-build (blocks 0..1364) ---------------
//                  + count/geometry (blocks 1365..2388) --------------------
// Count part persists evec[e] = {ux,uy,uz,tt} so the edge kernel never
// touches pos (6 scattered loads + sqrt removed from the hot kernel).
// Out-of-range edges (tt>=21, message provably zero) are excluded from
// the dst-degree counts entirely.
__global__ __launch_bounds__(256) void prep_kernel(
    const float* __restrict__ Wt1, const float* __restrict__ Wt2,
    float* __restrict__ T,
    const int* __restrict__ ei, const float* __restrict__ pos,
    int* __restrict__ cd, int* __restrict__ cb, int* __restrict__ ebin,
    float4* __restrict__ evec)
{
    __shared__ int hist[NBINS];
    __shared__ float h[64];
    int t = threadIdx.x;

    if (blockIdx.x < TBLOCKS) {
        // ---- table part ----
        int entry = blockIdx.x;            // 0 .. 21*65-1
        int m = entry / 65;
        int g = entry - m * 65;
        float d0 = (float)g * (1.0f / TGRID);
        float d1 = d0 - 1.0f;
        int j0 = m - 1, j1 = m;
        const float sq20 = 4.47213595499958f;

        float f0 = 0.f, f1 = 0.f;
        if (j0 >= 0 && j0 < 20)
            f0 = 1.14136f * expf(2.0f - 1.0f/(1.0f + d0) - 1.0f/(1.0f - d0)) * sq20;
        if (j1 >= 0 && j1 < 20)
            f1 = 1.14136f * expf(2.0f - 1.0f/(1.0f + d1) - 1.0f/(1.0f - d1)) * sq20;
        j0 = j0 < 0 ? 0 : (j0 > 19 ? 19 : j0);
        j1 = j1 < 0 ? 0 : (j1 > 19 ? 19 : j1);

        if (t < 64) {
            float a = fmaf(f0, Wt1[j0*64 + t], f1 * Wt1[j1*64 + t])
                      * 0.22360679774997896f;
            h[t] = 1.679177f * a / (1.0f + expf(-a));
        }
        __syncthreads();

        const float sc = 0.011048543456039806f;
        for (int e2 = t; e2 < TENT; e2 += 256) {
            int i = e2 / 24;
            int c = e2 - i * 24;
            float v = 0.f;
            if (c < 22) {
                int widx = (c < 16) ? (i*16 + c)
                         : (c < 20) ? (256 + i*4 + (c - 16))
                                    : (320 + i*2 + (c - 20));
                for (int k = 0; k < 64; ++k)
                    v = fmaf(h[k], Wt2[k*352 + widx], v);
                v *= sc;
            }
            T[(size_t)entry * TENT + e2] = v;
        }
    } else {
        // ---- count + geometry part ----
        for (int b = t; b < NBINS; b += 256) hist[b] = 0;
        __syncthreads();

        int e = (blockIdx.x - TBLOCKS) * 256 + t;
        int s = ei[e];
        int d = ei[N_EDGES + e];
        float px = pos[d*3+0] - pos[s*3+0];
        float py = pos[d*3+1] - pos[s*3+1];
        float pz = pos[d*3+2] - pos[s*3+2];
        float dist = sqrtf(px*px + py*py + pz*pz + 1e-12f);
        float rinv = 1.0f / dist;
        float tt = dist * 4.2f;
        evec[e] = make_float4(px*rinv, py*rinv, pz*rinv, tt);

        int bin;
        if (!(tt < 21.0f)) {
            bin = NBINS - 1;                 // zero-message edge: not counted
        } else {
            int m = (int)tt;
            float gf = (tt - (float)m) * (float)TGRID;
            int g0 = (int)gf; if (g0 > TGRID-1) g0 = TGRID-1;
            bin = m * TGRID + g0;
            atomicAdd(&cd[d], 1);            // 32k addresses: cheap
        }
        ebin[e] = bin;
        atomicAdd(&hist[bin], 1);
        __syncthreads();

        for (int b = t; b < NBINS; b += 256) {
            int c = hist[b];
            if (c) atomicAdd(&cb[b], c);
        }
    }
}

// dual scan: block 0 scans (c0,s0), block 1 scans (c1,s1). 32768 each.
__global__ __launch_bounds__(1024) void scan2_kernel(
    int* __restrict__ c0, int* __restrict__ s0arr,
    int* __restrict__ c1, int* __restrict__ s1arr)
{
    int* cursor = (blockIdx.x == 0) ? c0 : c1;
    int* start  = (blockIdx.x == 0) ? s0arr : s1arr;
    __shared__ int partial[1024];
    int tid = threadIdx.x;
    int base = tid * 32;
    int v[32];
    int s = 0;
    #pragma unroll
    for (int j = 0; j < 32; ++j) { v[j] = cursor[base + j]; s += v[j]; }
    partial[tid] = s;
    __syncthreads();
    for (int off = 1; off < 1024; off <<= 1) {
        int t = (tid >= off) ? partial[tid - off] : 0;
        __syncthreads();
        partial[tid] += t;
        __syncthreads();
    }
    int run = (tid > 0) ? partial[tid - 1] : 0;
    #pragma unroll
    for (int j = 0; j < 32; ++j) {
        start[base + j] = run;
        cursor[base + j] = run;
        run += v[j];
    }
    if (tid == 1023) start[32768] = run;
}

// ---------------- fill: two-level; emits int4 {e, src, dst, 0} ------------
__global__ __launch_bounds__(256) void fill_bins_kernel(
    const int* __restrict__ ebin, const int* __restrict__ ei,
    int* __restrict__ cursor_bin,            // pre-scanned starts, consumed
    int4* __restrict__ binfo)
{
    __shared__ int hist[NBINS];
    __shared__ int rbase[NBINS];
    for (int b = threadIdx.x; b < NBINS; b += 256) hist[b] = 0;
    __syncthreads();

    int e = blockIdx.x * 256 + threadIdx.x;
    int bin = ebin[e];
    atomicAdd(&hist[bin], 1);
    __syncthreads();

    for (int b = threadIdx.x; b < NBINS; b += 256) {
        int c = hist[b];
        if (c) rbase[b] = atomicAdd(&cursor_bin[b], c);  // distinct addrs/wave
        hist[b] = 0;                                     // reuse as local cursor
    }
    __syncthreads();

    int lr = atomicAdd(&hist[bin], 1);       // LDS local rank
    int slot = rbase[bin] + lr;
    binfo[slot] = make_int4(e, ei[e], ei[N_EDGES + e], 0);
}

// ---------------- Kernel 3: binned per-edge, fused lerp -------------------
// No pos access, no sqrt: geometry comes from evec[e]. Out-of-range edges
// exit before slot allocation (they are not in the dst counts).
__global__ __launch_bounds__(256) void edge_table_binned(
    const float4* __restrict__ evec,
    const float* __restrict__ T, const float* __restrict__ znode,
    const int4* __restrict__ binfo,
    unsigned short* __restrict__ tp, int* __restrict__ cursor,
    int2* __restrict__ elist2)
{
    int idx = blockIdx.x * 256 + threadIdx.x;
    int4 bf = binfo[idx];
    int e   = bf.x;
    int src = bf.y;
    int dst = bf.z;

    float4 ev = evec[e];
    float tt = ev.w;
    if (!(tt < 21.0f)) return;       // zero message, not in dst counts

    int slot = atomicAdd(&cursor[dst], 1);
    elist2[slot] = make_int2(e, idx);

    uint4* d4 = (uint4*)(tp + (size_t)idx * TPW);   // binned layout

    float ux = ev.x, uy = ev.y, uz = ev.z;

    int m  = (int)tt;                // 0..20
    float d0 = tt - (float)m;
    float gf = d0 * (float)TGRID;
    int g0 = (int)gf; if (g0 > TGRID-1) g0 = TGRID-1;
    float fr = gf - (float)g0;

    const float4* r0 = (const float4*)(T + (size_t)(m*65 + g0) * TENT);
    const float4* r1 = r0 + (TENT/4);    // next d0 grid point (contiguous)

    // aligned vector z loads
    const float4* zp = (const float4*)(znode + (size_t)src * 16);
    float4 zq0 = zp[0], zq1 = zp[1], zq2 = zp[2], zq3 = zp[3];
    float z[16] = {zq0.x, zq0.y, zq0.z, zq0.w,
                   zq1.x, zq1.y, zq1.z, zq1.w,
                   zq2.x, zq2.y, zq2.z, zq2.w,
                   zq3.x, zq3.y, zq3.z, zq3.w};

    float acc[24];
    #pragma unroll
    for (int c = 0; c < 24; ++c) acc[c] = 0.f;

    #pragma unroll
    for (int i = 0; i < 16; ++i) {
        float zi = z[i];
        #pragma unroll
        for (int q = 0; q < 6; ++q) {
            float4 v0 = r0[i*6 + q];
            float4 v1 = r1[i*6 + q];
            float w;
            w = fmaf(fr, v1.x - v0.x, v0.x); acc[q*4+0] = fmaf(zi, w, acc[q*4+0]);
            w = fmaf(fr, v1.y - v0.y, v0.y); acc[q*4+1] = fmaf(zi, w, acc[q*4+1]);
            w = fmaf(fr, v1.z - v0.z, v0.z); acc[q*4+2] = fmaf(zi, w, acc[q*4+2]);
            w = fmaf(fr, v1.w - v0.w, v0.w); acc[q*4+3] = fmaf(zi, w, acc[q*4+3]);
        }
    }

    float vals[38];
    #pragma unroll
    for (int c = 0; c < 22; ++c) vals[c] = acc[c];

    const float s3  = 1.7320508075688772f;
    const float s15 = 3.872983346207417f;
    const float s5  = 2.23606797749979f;
    float sh1x = s3*ux, sh1y = s3*uy, sh1z = s3*uz;
    float sh2a = s15 * ux * uz;
    float sh2b = s15 * ux * uy;
    float sh2c = s5 * (uy*uy - 0.5f*(ux*ux + uz*uz));
    float sh2d = s15 * uy * uz;
    float sh2e = 0.5f * s15 * (uz*uz - ux*ux);

    // expand T first (consumes vals[20..21]), then V descending (16..19)
    #pragma unroll
    for (int u = 1; u >= 0; --u) {
        float v = vals[20 + u];
        vals[28 + u*5 + 0] = v * sh2a;
        vals[28 + u*5 + 1] = v * sh2b;
        vals[28 + u*5 + 2] = v * sh2c;
        vals[28 + u*5 + 3] = v * sh2d;
        vals[28 + u*5 + 4] = v * sh2e;
    }
    #pragma unroll
    for (int u = 3; u >= 0; --u) {
        float v = vals[16 + u];
        vals[16 + u*3 + 0] = v * sh1x;
        vals[16 + u*3 + 1] = v * sh1y;
        vals[16 + u*3 + 2] = v * sh1z;
    }

    // fp16 pack; store each uint4 immediately (short live ranges)
    d4[0] = make_uint4(pkh(vals[0], vals[1]),  pkh(vals[2], vals[3]),
                       pkh(vals[4], vals[5]),  pkh(vals[6], vals[7]));
    d4[1] = make_uint4(pkh(vals[8], vals[9]),  pkh(vals[10], vals[11]),
                       pkh(vals[12], vals[13]),pkh(vals[14], vals[15]));
    d4[2] = make_uint4(pkh(vals[16], vals[17]),pkh(vals[18], vals[19]),
                       pkh(vals[20], vals[21]),pkh(vals[22], vals[23]));
    d4[3] = make_uint4(pkh(vals[24], vals[25]),pkh(vals[26], vals[27]),
                       pkh(vals[28], vals[29]),pkh(vals[30], vals[31]));
    d4[4] = make_uint4(pkh(vals[32], vals[33]),pkh(vals[34], vals[35]),
                       pkh(vals[36], vals[37]),0);
}

// ---------------- Kernel 4: gather segment-sum, SORTED (deterministic) ------
__global__ __launch_bounds__(256) void gather_sorted_kernel(
    const unsigned short* __restrict__ tp, const int* __restrict__ start,
    const int2* __restrict__ elist2, float* __restrict__ out)
{
    __shared__ int sid[4][128];
    __shared__ int srw[4][128];
    __shared__ int so[4][128];
    int wave = threadIdx.x >> 6;
    int lane = threadIdx.x & 63;
    int n = blockIdx.x * 4 + wave;          // grid == N_NODES/4, always valid
    int s0 = start[n], s1 = start[n+1];
    int K = s1 - s0;
    bool small = (K <= 128);

    if (small) {
        for (int j = lane; j < K; j += 64) {
            int2 v = elist2[s0 + j];
            sid[wave][j] = v.x;
            srw[wave][j] = v.y;
        }
    }
    __syncthreads();
    if (small) {
        for (int j = lane; j < K; j += 64) {
            int v = sid[wave][j];
            int r = 0;
            for (int q = 0; q < K; ++q) r += (sid[wave][q] < v);
            so[wave][r] = srw[wave][j];   // edge ids distinct -> permutation
        }
    }
    __syncthreads();

    if (lane < 19) {
        float acc0 = 0.f, acc1 = 0.f;
        if (small) {
            for (int j = 0; j < K; ++j) {
                const unsigned* row = (const unsigned*)
                    (tp + (size_t)so[wave][j] * TPW);
                unsigned v = row[lane];
                acc0 += __half2float(__ushort_as_half((unsigned short)(v & 0xffffu)));
                acc1 += __half2float(__ushort_as_half((unsigned short)(v >> 16)));
            }
        } else {
            for (int j = s0; j < s1; ++j) {
                int2 ev = elist2[j];
                const unsigned* row = (const unsigned*)
                    (tp + (size_t)ev.y * TPW);
                unsigned v = row[lane];
                acc0 += __half2float(__ushort_as_half((unsigned short)(v & 0xffffu)));
                acc1 += __half2float(__ushort_as_half((unsigned short)(v >> 16)));
            }
        }
        out[n*OUTC + 16 + 2*lane] = acc0;
        out[n*OUTC + 16 + 2*lane + 1] = acc1;
    }
}

// ---------------- fallback (atomics) if ws too small -----------------
__global__ __launch_bounds__(256) void edge_kernel_atomic(
    const float* __restrict__ pos, const int* __restrict__ ei,
    const float* __restrict__ Wt1, const float* __restrict__ Wt2,
    float* out)
{
    int e = blockIdx.x * blockDim.x + threadIdx.x;
    if (e >= N_EDGES) return;
    int src = ei[e];
    int dst = ei[N_EDGES + e];
    float px = pos[dst*3+0] - pos[src*3+0];
    float py = pos[dst*3+1] - pos[src*3+1];
    float pz = pos[dst*3+2] - pos[src*3+2];
    float dist = sqrtf(px*px + py*py + pz*pz + 1e-12f);
    float rinv = 1.0f / dist;
    float ux = px*rinv, uy = py*rinv, uz = pz*rinv;
    const float step = 5.0f / 21.0f;
    float tt = dist / step;
    int m  = (int)floorf(tt);
    int j0 = m - 1, j1 = m;
    float d0 = tt - (float)m, d1 = d0 - 1.0f;
    const float sq20 = 4.47213595499958f;
    float f0 = 0.f, f1 = 0.f;
    if (j0 >= 0 && j0 < 20)
        f0 = 1.14136f * expf(2.0f - 1.0f/(1.0f + d0) - 1.0f/(1.0f - d0)) * sq20;
    if (j1 >= 0 && j1 < 20 && d1 > -1.0f)
        f1 = 1.14136f * expf(2.0f - 1.0f/(1.0f + d1) - 1.0f/(1.0f - d1)) * sq20;
    if (f0 == 0.f && f1 == 0.f) return;
    j0 = j0 < 0 ? 0 : (j0 > 19 ? 19 : j0);
    j1 = j1 < 0 ? 0 : (j1 > 19 ? 19 : j1);
    const float* w1a = Wt1 + j0*64;
    const float* w1b = Wt1 + j1*64;
    float z[16];
    #pragma unroll
    for (int i = 0; i < 16; ++i) z[i] = out[src*OUTC + i];
    const float rsq20 = 0.22360679774997896f;
    const float snorm = 1.679177f;
    float accS[16], accV[4], accT[2];
    #pragma unroll
    for (int u = 0; u < 16; ++u) accS[u] = 0.f;
    #pragma unroll
    for (int u = 0; u < 4; ++u) accV[u] = 0.f;
    #pragma unroll
    for (int u = 0; u < 2; ++u) accT[u] = 0.f;
    for (int k = 0; k < 64; ++k) {
        float a = fmaf(f0, w1a[k], f1 * w1b[k]) * rsq20;
        float hk = snorm * a / (1.0f + expf(-a));
        const float* row = Wt2 + k*352;
        float tmp[16];
        #pragma unroll
        for (int u = 0; u < 16; ++u) tmp[u] = 0.f;
        #pragma unroll
        for (int i = 0; i < 16; ++i) {
            float zi = z[i];
            #pragma unroll
            for (int u = 0; u < 16; ++u) tmp[u] = fmaf(zi, row[i*16 + u], tmp[u]);
        }
        #pragma unroll
        for (int u = 0; u < 16; ++u) accS[u] = fmaf(hk, tmp[u], accS[u]);
        float tv[4] = {0.f,0.f,0.f,0.f};
        #pragma unroll
        for (int i = 0; i < 16; ++i) {
            float zi = z[i];
            #pragma unroll
            for (int u = 0; u < 4; ++u) tv[u] = fmaf(zi, row[256 + i*4 + u], tv[u]);
        }
        #pragma unroll
        for (int u = 0; u < 4; ++u) accV[u] = fmaf(hk, tv[u], accV[u]);
        float tw[2] = {0.f,0.f};
        #pragma unroll
        for (int i = 0; i < 16; ++i) {
            float zi = z[i];
            #pragma unroll
            for (int u = 0; u < 2; ++u) tw[u] = fmaf(zi, row[320 + i*2 + u], tw[u]);
        }
        #pragma unroll
        for (int u = 0; u < 2; ++u) accT[u] = fmaf(hk, tw[u], accT[u]);
    }
    const float sc = 0.125f * 0.25f * 0.35355339059327373f;
    const float s3  = 1.7320508075688772f;
    const float s15 = 3.872983346207417f;
    const float s5  = 2.23606797749979f;
    float sh1x = s3*ux, sh1y = s3*uy, sh1z = s3*uz;
    float sh2[5];
    sh2[0] = s15 * ux * uz;
    sh2[1] = s15 * ux * uy;
    sh2[2] = s5 * (uy*uy - 0.5f*(ux*ux + uz*uz));
    sh2[3] = s15 * uy * uz;
    sh2[4] = 0.5f * s15 * (uz*uz - ux*ux);
    float* orow = out + dst*OUTC + 16;
    #pragma unroll
    for (int u = 0; u < 16; ++u) atomicAdd(&orow[u], accS[u] * sc);
    #pragma unroll
    for (int u = 0; u < 4; ++u) {
        float v = accV[u] * sc;
        atomicAdd(&orow[16 + u*3 + 0], v * sh1x);
        atomicAdd(&orow[16 + u*3 + 1], v * sh1y);
        atomicAdd(&orow[16 + u*3 + 2], v * sh1z);
    }
    #pragma unroll
    for (int u = 0; u < 2; ++u) {
        float v = accT[u] * sc;
        #pragma unroll
        for (int mm = 0; mm < 5; ++mm)
            atomicAdd(&orow[28 + u*5 + mm], v * sh2[mm]);
    }
}

extern "C" void kernel_launch(void* const* d_in, const int* in_sizes, int n_in,
                              void* d_out, int out_size, void* d_ws, size_t ws_size,
                              hipStream_t stream) {
    const float* x   = (const float*)d_in[0];
    const float* pos = (const float*)d_in[1];
    const int*   ei  = (const int*)d_in[2];
    const float* We1 = (const float*)d_in[3];
    const float* We2 = (const float*)d_in[4];
    const float* Wt1 = (const float*)d_in[5];
    const float* Wt2 = (const float*)d_in[6];
    float* out = (float*)d_out;

    char* base = (char*)d_ws;
    size_t off = 0;
    unsigned short* tp = (unsigned short*)(base + off);
    off += (size_t)N_EDGES * TPW * 2;                    // fp16 rows, 21 MB
    float* T  = (float*)(base + off);       off += (size_t)TBLOCKS * TENT * 4;  // 2.1 MB
    float* znode = (float*)(base + off);    off += (size_t)N_NODES * 16 * 4;    // 2 MB
    float4* evec = (float4*)(base + off);   off += (size_t)N_EDGES * 16;        // 4 MB
    int* cursor_dst = (int*)(base + off);   off += (size_t)32768 * 4;
    int* cursor_bin = (int*)(base + off);   off += (size_t)32768 * 4;   // adjacent: one memset
    int* start_dst  = (int*)(base + off);   off += (size_t)32769 * 4;
    int* start_bin  = (int*)(base + off);   off += (size_t)32769 * 4;
    int* ebin       = (int*)(base + off);   off += (size_t)N_EDGES * 4;
    int4* binfo     = (int4*)(base + off);  off += (size_t)N_EDGES * 16;
    int2* elist2    = (int2*)(base + off);  off += (size_t)N_EDGES * 8;
    size_t need = off;

    if (ws_size >= need) {
        node_emb_kernel<<<N_NODES/256, 256, 0, stream>>>(x, We1, We2, out, znode);
        hipMemsetAsync(cursor_dst, 0, (size_t)2 * 32768 * 4, stream);
        prep_kernel<<<TBLOCKS + N_EDGES/256, 256, 0, stream>>>(
            Wt1, Wt2, T, ei, pos, cursor_dst, cursor_bin, ebin, evec);
        scan2_kernel<<<2, 1024, 0, stream>>>(cursor_dst, start_dst,
                                             cursor_bin, start_bin);
        fill_bins_kernel<<<N_EDGES/256, 256, 0, stream>>>(ebin, ei, cursor_bin,
                                                          binfo);
        edge_table_binned<<<N_EDGES/256, 256, 0, stream>>>(evec, T, znode,
                                                           binfo, tp,
                                                           cursor_dst, elist2);
        gather_sorted_kernel<<<N_NODES/4, 256, 0, stream>>>(tp, start_dst,
                                                            elist2, out);
    } else {
        hipMemsetAsync(out, 0, (size_t)out_size * sizeof(float), stream);
        node_emb_kernel<<<N_NODES/256, 256, 0, stream>>>(x, We1, We2, out,
                                                         (float*)d_ws);
        edge_kernel_atomic<<<N_EDGES/256, 256, 0, stream>>>(pos, ei, Wt1, Wt2, out);
    }
}